// Round 1
// baseline (23960.455 us; speedup 1.0000x reference)
//
#include <hip/hip_runtime.h>
#include <math.h>

// ---------------- problem constants ----------------
constexpr int Bn   = 32;
constexpr int Dn   = 768;
constexpr int NHn  = 12;
constexpr int HDn  = 64;
constexpr int Ln   = 12;
constexpr int DFFn = 3072;
constexpr int OUTn = 1000;
constexpr int Sn   = 197;          // 14*14 + 1 tokens
constexpr int Mrows = Bn * Sn;     // 6304
constexpr int NPATCH = 196;

// ---------------- GEMM: C = act(A[M,K] @ W[K,N] + bias) (+res) ----------------
// 128x128 tile, BK=16, 256 threads, 8x8 micro-tile per thread.
constexpr int BM = 128, BN = 128, BK = 16;

template<int ACT, bool RES>   // ACT: 0 none, 1 gelu(exact), 2 tanh
__global__ __launch_bounds__(256) void gemm_kernel(
    const float* __restrict__ A, const float* __restrict__ W,
    const float* __restrict__ bias, const float* __restrict__ res,
    float* __restrict__ out, int M, int N, int K)
{
  __shared__ __align__(16) float As[BK][BM + 8];   // stride 136 words (544B, 16B-aligned rows)
  __shared__ __align__(16) float Bs[BK][BN + 8];
  const int tid = threadIdx.x;
  const int tx = tid & 15, ty = tid >> 4;
  const int bm = blockIdx.y * BM;
  const int bn = blockIdx.x * BN;

  float acc[8][8];
  #pragma unroll
  for (int i = 0; i < 8; ++i)
    #pragma unroll
    for (int j = 0; j < 8; ++j) acc[i][j] = 0.f;

  for (int k0 = 0; k0 < K; k0 += BK) {
    // A tile: 128 rows x 16 cols = 512 float4 loads (transposed store)
    #pragma unroll
    for (int i = 0; i < 2; ++i) {
      int idx = tid + i * 256;
      int r = idx >> 2, c4 = (idx & 3) * 4;
      int gr = bm + r;
      float4 v = make_float4(0.f, 0.f, 0.f, 0.f);
      if (gr < M) v = *(const float4*)(A + (size_t)gr * K + k0 + c4);
      As[c4 + 0][r] = v.x; As[c4 + 1][r] = v.y;
      As[c4 + 2][r] = v.z; As[c4 + 3][r] = v.w;
    }
    // B tile: 16 rows x 128 cols = 512 float4 loads
    #pragma unroll
    for (int i = 0; i < 2; ++i) {
      int idx = tid + i * 256;
      int r = idx >> 5, c4 = (idx & 31) * 4;
      int gc = bn + c4;
      const float* wp = W + (size_t)(k0 + r) * N + gc;
      float4 v = make_float4(0.f, 0.f, 0.f, 0.f);
      if (gc + 3 < N) {
        v = *(const float4*)wp;
      } else {
        if (gc + 0 < N) v.x = wp[0];
        if (gc + 1 < N) v.y = wp[1];
        if (gc + 2 < N) v.z = wp[2];
        if (gc + 3 < N) v.w = wp[3];
      }
      *(float4*)&Bs[r][c4] = v;
    }
    __syncthreads();
    #pragma unroll
    for (int kk = 0; kk < BK; ++kk) {
      float a[8], b[8];
      *(float4*)&a[0] = *(const float4*)&As[kk][ty * 8];
      *(float4*)&a[4] = *(const float4*)&As[kk][ty * 8 + 4];
      *(float4*)&b[0] = *(const float4*)&Bs[kk][tx * 8];
      *(float4*)&b[4] = *(const float4*)&Bs[kk][tx * 8 + 4];
      #pragma unroll
      for (int i = 0; i < 8; ++i)
        #pragma unroll
        for (int j = 0; j < 8; ++j)
          acc[i][j] = fmaf(a[i], b[j], acc[i][j]);
    }
    __syncthreads();
  }
  // epilogue
  #pragma unroll
  for (int i = 0; i < 8; ++i) {
    int r = bm + ty * 8 + i;
    if (r >= M) continue;
    #pragma unroll
    for (int j = 0; j < 8; ++j) {
      int c = bn + tx * 8 + j;
      if (c >= N) continue;
      float v = acc[i][j] + bias[c];
      if (ACT == 1) v = 0.5f * v * (1.f + erff(v * 0.70710678118654752f));
      else if (ACT == 2) v = tanhf(v);
      if (RES) v += res[(size_t)r * N + c];
      out[(size_t)r * N + c] = v;
    }
  }
}

// ---------------- patchify: x[B,C,224,224] -> patches[B*196, 768] ----------------
__global__ __launch_bounds__(256) void patchify_kernel(const float* __restrict__ x,
                                                       float* __restrict__ p)
{
  size_t i = (size_t)blockIdx.x * 256 + threadIdx.x;
  constexpr size_t total = (size_t)Bn * NPATCH * 768;
  if (i >= total) return;
  int k = (int)(i % 768);
  size_t m = i / 768;
  int b = (int)(m / NPATCH), pp = (int)(m % NPATCH);
  int py = pp / 14, px = pp % 14;
  int c = k >> 8, ph = (k >> 4) & 15, pw = k & 15;
  p[i] = x[(((size_t)(b * 3 + c)) * 224 + py * 16 + ph) * 224 + px * 16 + pw];
}

// ---------------- assemble: tokens+cls+pos -> [B,S,D] ----------------
__global__ __launch_bounds__(256) void assemble_kernel(const float* __restrict__ tok,
                                                       const float* __restrict__ cls,
                                                       const float* __restrict__ pos,
                                                       float* __restrict__ outp)
{
  size_t i = (size_t)blockIdx.x * 256 + threadIdx.x;
  constexpr size_t total = (size_t)Bn * Sn * Dn;
  if (i >= total) return;
  int d = (int)(i % Dn);
  size_t m = i / Dn;
  int s = (int)(m % Sn);
  size_t b = m / Sn;
  float v = (s == 0) ? cls[d] : tok[(b * NPATCH + (s - 1)) * Dn + d];
  outp[i] = v + pos[s * Dn + d];
}

// ---------------- LayerNorm over D=768, one block per row ----------------
__global__ __launch_bounds__(256) void ln_kernel(const float* __restrict__ x, size_t xstride,
                                                 const float* __restrict__ g,
                                                 const float* __restrict__ bt,
                                                 float* __restrict__ out)
{
  const int row = blockIdx.x;
  const int tid = threadIdx.x;
  const float* xr = x + (size_t)row * xstride;
  float v0 = xr[tid], v1 = xr[tid + 256], v2 = xr[tid + 512];
  float s = v0 + v1 + v2;
  float q = v0 * v0 + v1 * v1 + v2 * v2;
  #pragma unroll
  for (int o = 32; o > 0; o >>= 1) { s += __shfl_down(s, o); q += __shfl_down(q, o); }
  __shared__ float sa[4], sb[4];
  int w = tid >> 6, lane = tid & 63;
  if (lane == 0) { sa[w] = s; sb[w] = q; }
  __syncthreads();
  if (tid == 0) {
    float ts = sa[0] + sa[1] + sa[2] + sa[3];
    float tq = sb[0] + sb[1] + sb[2] + sb[3];
    sa[0] = ts; sb[0] = tq;
  }
  __syncthreads();
  s = sa[0]; q = sb[0];
  const float mean = s * (1.f / 768.f);
  const float var  = q * (1.f / 768.f) - mean * mean;
  const float inv  = rsqrtf(var + 1e-5f);
  float* orow = out + (size_t)row * Dn;
  orow[tid]       = (v0 - mean) * inv * g[tid]       + bt[tid];
  orow[tid + 256] = (v1 - mean) * inv * g[tid + 256] + bt[tid + 256];
  orow[tid + 512] = (v2 - mean) * inv * g[tid + 512] + bt[tid + 512];
}

// ---------------- attention: one block per (b, head), one thread per query row ----------------
// qkv layout [B,S,3D] with q = [0,D), k = [D,2D), v = [2D,3D); head h = cols h*64..h*64+63.
__global__ __launch_bounds__(256) void attn_kernel(const float* __restrict__ qkv,
                                                   float* __restrict__ ctx)
{
  const int bh = blockIdx.x;
  const int b = bh / NHn, h = bh % NHn;
  const int tid = threadIdx.x;
  __shared__ float Ks[64][HDn + 1];
  __shared__ float Vs[64][HDn + 1];

  float qreg[HDn];
  if (tid < Sn) {
    const float* qp = qkv + ((size_t)(b * Sn + tid)) * (3 * Dn) + h * HDn;
    #pragma unroll
    for (int d = 0; d < HDn; ++d) qreg[d] = qp[d];
  }
  float mrun = -1e30f, lsum = 0.f;
  float acc[HDn];
  #pragma unroll
  for (int d = 0; d < HDn; ++d) acc[d] = 0.f;

  const float scale = 0.125f;  // 1/sqrt(64)

  for (int kc = 0; kc < Sn; kc += 64) {
    const int nk = (Sn - kc) < 64 ? (Sn - kc) : 64;
    __syncthreads();
    #pragma unroll
    for (int i = 0; i < 16; ++i) {
      int idx = tid + i * 256;          // 0..4095
      int j = idx >> 6, d = idx & 63;
      if (kc + j < Sn) {
        const float* kp = qkv + ((size_t)(b * Sn + kc + j)) * (3 * Dn) + Dn + h * HDn;
        Ks[j][d] = kp[d];
        Vs[j][d] = kp[Dn + d];
      }
    }
    __syncthreads();
    if (tid < Sn) {
      for (int j = 0; j < nk; ++j) {
        float sc = 0.f;
        #pragma unroll
        for (int d = 0; d < HDn; ++d) sc = fmaf(qreg[d], Ks[j][d], sc);
        sc *= scale;
        float mn = fmaxf(mrun, sc);
        float corr = expf(mrun - mn);
        float p = expf(sc - mn);
        lsum = lsum * corr + p;
        #pragma unroll
        for (int d = 0; d < HDn; ++d) acc[d] = fmaf(acc[d], corr, p * Vs[j][d]);
        mrun = mn;
      }
    }
  }
  if (tid < Sn) {
    float r = 1.f / lsum;
    float* op = ctx + ((size_t)(b * Sn + tid)) * Dn + h * HDn;
    #pragma unroll
    for (int d = 0; d < HDn; ++d) op[d] = acc[d] * r;
  }
}

// ---------------- host launch helpers ----------------
static inline void run_gemm(int act, bool res,
                            const float* A, const float* W, const float* bias,
                            const float* resp, float* out, int M, int N, int K,
                            hipStream_t st)
{
  dim3 grid((N + BN - 1) / BN, (M + BM - 1) / BM);
  if (res) {
    gemm_kernel<0, true><<<grid, 256, 0, st>>>(A, W, bias, resp, out, M, N, K);
  } else if (act == 1) {
    gemm_kernel<1, false><<<grid, 256, 0, st>>>(A, W, bias, nullptr, out, M, N, K);
  } else if (act == 2) {
    gemm_kernel<2, false><<<grid, 256, 0, st>>>(A, W, bias, nullptr, out, M, N, K);
  } else {
    gemm_kernel<0, false><<<grid, 256, 0, st>>>(A, W, bias, nullptr, out, M, N, K);
  }
}

extern "C" void kernel_launch(void* const* d_in, const int* in_sizes, int n_in,
                              void* d_out, int out_size, void* d_ws, size_t ws_size,
                              hipStream_t stream)
{
  const float* x      = (const float*)d_in[0];
  const float* emb_w  = (const float*)d_in[1];
  const float* emb_b  = (const float*)d_in[2];
  const float* cls    = (const float*)d_in[3];
  const float* pos    = (const float*)d_in[4];
  const float* pre_g  = (const float*)d_in[5];
  const float* pre_b  = (const float*)d_in[6];
  const float* ln1_g  = (const float*)d_in[7];
  const float* ln1_b  = (const float*)d_in[8];
  const float* qkv_w  = (const float*)d_in[9];
  const float* qkv_b  = (const float*)d_in[10];
  const float* proj_w = (const float*)d_in[11];
  const float* proj_b = (const float*)d_in[12];
  const float* ln2_g  = (const float*)d_in[13];
  const float* ln2_b  = (const float*)d_in[14];
  const float* fc1_w  = (const float*)d_in[15];
  const float* fc1_b  = (const float*)d_in[16];
  const float* fc2_w  = (const float*)d_in[17];
  const float* fc2_b  = (const float*)d_in[18];
  const float* post_g = (const float*)d_in[19];
  const float* post_b = (const float*)d_in[20];
  const float* h1_w   = (const float*)d_in[21];
  const float* h1_b   = (const float*)d_in[22];
  const float* h2_w   = (const float*)d_in[23];
  const float* h2_b   = (const float*)d_in[24];
  float* out = (float*)d_out;

  // workspace layout (floats)
  const size_t HN = (size_t)Mrows * Dn;        // 4,841,472
  const size_t QN = (size_t)Mrows * 3 * Dn;    // 14,524,416
  float* hbuf = (float*)d_ws;
  float* ybuf = hbuf + HN;
  float* qbuf = ybuf + HN;                     // qkv / patch-embed tokens / head tmp
  float* mbuf = qbuf + QN;                     // mlp / patches

  // 1) patchify into mbuf [6272,768]
  patchify_kernel<<<(Bn * NPATCH * Dn) / 256, 256, 0, stream>>>(x, mbuf);
  // 2) patch embed GEMM -> qbuf [6272,768]
  run_gemm(0, false, mbuf, emb_w, emb_b, nullptr, qbuf, Bn * NPATCH, Dn, Dn, stream);
  // 3) assemble cls+pos -> ybuf [B,S,D]
  assemble_kernel<<<(Bn * Sn * Dn) / 256, 256, 0, stream>>>(qbuf, cls, pos, ybuf);
  // 4) pre-LN -> hbuf
  ln_kernel<<<Mrows, 256, 0, stream>>>(ybuf, (size_t)Dn, pre_g, pre_b, hbuf);

  for (int l = 0; l < Ln; ++l) {
    const float* g1 = ln1_g + (size_t)l * Dn;
    const float* b1 = ln1_b + (size_t)l * Dn;
    const float* qw = qkv_w + (size_t)l * Dn * 3 * Dn;
    const float* qb = qkv_b + (size_t)l * 3 * Dn;
    const float* pw = proj_w + (size_t)l * Dn * Dn;
    const float* pb = proj_b + (size_t)l * Dn;
    const float* g2 = ln2_g + (size_t)l * Dn;
    const float* b2 = ln2_b + (size_t)l * Dn;
    const float* f1w = fc1_w + (size_t)l * Dn * DFFn;
    const float* f1b = fc1_b + (size_t)l * DFFn;
    const float* f2w = fc2_w + (size_t)l * DFFn * Dn;
    const float* f2b = fc2_b + (size_t)l * Dn;

    // LN1: h -> y
    ln_kernel<<<Mrows, 256, 0, stream>>>(hbuf, (size_t)Dn, g1, b1, ybuf);
    // QKV: y @ qw + qb -> qbuf [M, 3D]
    run_gemm(0, false, ybuf, qw, qb, nullptr, qbuf, Mrows, 3 * Dn, Dn, stream);
    // attention: qbuf -> ybuf (ctx)
    attn_kernel<<<Bn * NHn, 256, 0, stream>>>(qbuf, ybuf);
    // proj + residual: h = h + ctx @ pw + pb
    run_gemm(0, true, ybuf, pw, pb, hbuf, hbuf, Mrows, Dn, Dn, stream);
    // LN2: h -> y
    ln_kernel<<<Mrows, 256, 0, stream>>>(hbuf, (size_t)Dn, g2, b2, ybuf);
    // fc1 + gelu: y @ f1w -> mbuf [M, DFF]
    run_gemm(1, false, ybuf, f1w, f1b, nullptr, mbuf, Mrows, DFFn, Dn, stream);
    // fc2 + residual: h = h + m @ f2w + f2b
    run_gemm(0, true, mbuf, f2w, f2b, hbuf, hbuf, Mrows, Dn, DFFn, stream);
  }

  // head: LN of h[:,0,:] (row stride S*D) -> ybuf [32,768]
  ln_kernel<<<Bn, 256, 0, stream>>>(hbuf, (size_t)Sn * Dn, post_g, post_b, ybuf);
  // tanh(y @ h1_w + h1_b) -> qbuf [32,768]
  run_gemm(2, false, ybuf, h1_w, h1_b, nullptr, qbuf, Bn, Dn, Dn, stream);
  // qbuf @ h2_w + h2_b -> out [32,1000]
  run_gemm(0, false, qbuf, h2_w, h2_b, nullptr, out, Bn, OUTn, Dn, stream);
}

// Round 3
// 8278.405 us; speedup vs baseline: 2.8943x; 2.8943x over previous
//
#include <hip/hip_runtime.h>
#include <hip/hip_bf16.h>
#include <math.h>
#include <cstdint>

// ---------------- problem constants ----------------
constexpr int Bn   = 32;
constexpr int Dn   = 768;
constexpr int NHn  = 12;
constexpr int HDn  = 64;
constexpr int Ln   = 12;
constexpr int DFFn = 3072;
constexpr int OUTn = 1000;
constexpr int Sn   = 197;          // 14*14 + 1 tokens
constexpr int Mrows = Bn * Sn;     // 6304
constexpr int NPATCH = 196;

typedef __attribute__((ext_vector_type(8))) short bf16x8;
typedef __attribute__((ext_vector_type(4))) float f32x4;

__device__ inline void store_val(float* p, float v) { *p = v; }
__device__ inline void store_val(__hip_bfloat16* p, float v) { *p = __float2bfloat16(v); }

// async global->LDS, 16B per lane; LDS dest = wave-uniform base + lane*16
__device__ inline void gload_lds16(const void* g, void* l) {
  auto gp = (const __attribute__((address_space(1))) unsigned int*)(uintptr_t)g;
  auto lp = (__attribute__((address_space(3))) unsigned int*)(uintptr_t)l;
  __builtin_amdgcn_global_load_lds(gp, lp, 16, 0, 0);
}

// ---------------- bf16 MFMA GEMM ----------------
// C[M,N] = act(A[M,K](bf16) @ Bt[N,K]^T(bf16) + bias) (+res fp32)
// 128x128 tile, BK=32, 256 threads = 4 waves (2x2), 64x64 per wave,
// 16x mfma_f32_16x16x32_bf16 per K-step. LDS XOR-swizzled (slot ^= r&3),
// staged via global_load_lds with pre-swizzled global source.
template<int ACT, bool RES, typename OT>   // ACT: 0 none, 1 gelu(exact)
__global__ __launch_bounds__(256) void bgemm_kernel(
    const __hip_bfloat16* __restrict__ A,
    const __hip_bfloat16* __restrict__ Bt,
    const float* __restrict__ bias,
    const float* __restrict__ res,
    OT* __restrict__ out, int M, int N, int K)
{
  __shared__ __hip_bfloat16 As[128 * 32];   // 8 KB
  __shared__ __hip_bfloat16 Bs[128 * 32];   // 8 KB
  const int tid  = threadIdx.x;
  const int w    = tid >> 6, lane = tid & 63;
  const int wm   = w >> 1,   wn   = w & 1;
  const int bm   = blockIdx.y * 128, bn = blockIdx.x * 128;
  const int kg   = lane >> 4, fr = lane & 15;

  f32x4 acc[4][4];
  #pragma unroll
  for (int i = 0; i < 4; ++i)
    #pragma unroll
    for (int j = 0; j < 4; ++j) acc[i][j] = (f32x4)(0.f);

  for (int k0 = 0; k0 < K; k0 += 32) {
    // ---- stage A & Bt tiles (each wave fills its contiguous 2 KB of each) ----
    #pragma unroll
    for (int i = 0; i < 2; ++i) {
      const int obase = w * 2048 + i * 1024;       // wave-uniform LDS byte base
      const int o  = obase + lane * 16;            // this lane's LDS byte
      const int r  = o >> 6;                       // tile row (64 B per row)
      const int ks = (((o >> 4) & 3) ^ (r & 3)) * 8;  // pre-swizzled k-slot
      {
        int gr = bm + r; if (gr >= M) gr = M - 1;  // clamp (epilogue masks)
        gload_lds16(A + (size_t)gr * K + k0 + ks, (char*)As + obase);
      }
      {
        const int gc = bn + r;                     // N is a multiple of 128 here
        gload_lds16(Bt + (size_t)gc * K + k0 + ks, (char*)Bs + obase);
      }
    }
    __syncthreads();

    // ---- fragments: A row = lane&15, k = (lane>>4)*8 + j (B symmetric on Bt) ----
    bf16x8 af[4], bfv[4];
    #pragma unroll
    for (int t = 0; t < 4; ++t) {
      const int r = wm * 64 + t * 16 + fr;
      af[t]  = *(const bf16x8*)((const char*)As + r * 64 + ((kg ^ (r & 3)) << 4));
      const int c = wn * 64 + t * 16 + fr;
      bfv[t] = *(const bf16x8*)((const char*)Bs + c * 64 + ((kg ^ (c & 3)) << 4));
    }
    #pragma unroll
    for (int mt = 0; mt < 4; ++mt)
      #pragma unroll
      for (int nt = 0; nt < 4; ++nt)
        acc[mt][nt] = __builtin_amdgcn_mfma_f32_16x16x32_bf16(af[mt], bfv[nt], acc[mt][nt], 0, 0, 0);
    __syncthreads();
  }

  // ---- epilogue: C/D col = lane&15, row = (lane>>4)*4 + j (m89-verified) ----
  #pragma unroll
  for (int nt = 0; nt < 4; ++nt) {
    const int cb = bn + wn * 64 + nt * 16 + fr;
    const float bs = bias[cb];
    #pragma unroll
    for (int mt = 0; mt < 4; ++mt) {
      #pragma unroll
      for (int j = 0; j < 4; ++j) {
        const int rb = bm + wm * 64 + mt * 16 + kg * 4 + j;
        if (rb >= M) continue;
        float v = acc[mt][nt][j] + bs;
        if (ACT == 1) v = 0.5f * v * (1.f + erff(v * 0.70710678118654752f));
        if (RES) v += res[(size_t)rb * N + cb];
        store_val(out + (size_t)rb * N + cb, v);
      }
    }
  }
}

// ---------------- transpose-convert: W[K,N] fp32 -> Wt[N,K] bf16 ----------------
__global__ __launch_bounds__(256) void convT_kernel(const float* __restrict__ W,
                                                    __hip_bfloat16* __restrict__ Wt,
                                                    int K, int N)
{
  __shared__ float t[32][33];
  const int k0 = blockIdx.y * 32, n0 = blockIdx.x * 32;
  const int r  = threadIdx.x >> 3, c4 = (threadIdx.x & 7) * 4;
  float4 v = *(const float4*)(W + (size_t)(k0 + r) * N + n0 + c4);
  t[r][c4 + 0] = v.x; t[r][c4 + 1] = v.y; t[r][c4 + 2] = v.z; t[r][c4 + 3] = v.w;
  __syncthreads();
  __hip_bfloat16* o = Wt + (size_t)(n0 + r) * K + k0 + c4;
  o[0] = __float2bfloat16(t[c4 + 0][r]);
  o[1] = __float2bfloat16(t[c4 + 1][r]);
  o[2] = __float2bfloat16(t[c4 + 2][r]);
  o[3] = __float2bfloat16(t[c4 + 3][r]);
}

// ---------------- fp32 GEMM (head only, M=32) ----------------
constexpr int BM = 128, BN = 128, BK = 16;
template<int ACT>   // 0 none, 2 tanh
__global__ __launch_bounds__(256) void gemm_kernel(
    const float* __restrict__ A, const float* __restrict__ W,
    const float* __restrict__ bias,
    float* __restrict__ out, int M, int N, int K)
{
  __shared__ __align__(16) float As[BK][BM + 8];
  __shared__ __align__(16) float Bsh[BK][BN + 8];
  const int tid = threadIdx.x;
  const int tx = tid & 15, ty = tid >> 4;
  const int bm = blockIdx.y * BM;
  const int bn = blockIdx.x * BN;

  float acc[8][8];
  #pragma unroll
  for (int i = 0; i < 8; ++i)
    #pragma unroll
    for (int j = 0; j < 8; ++j) acc[i][j] = 0.f;

  for (int k0 = 0; k0 < K; k0 += BK) {
    #pragma unroll
    for (int i = 0; i < 2; ++i) {
      int idx = tid + i * 256;
      int r = idx >> 2, c4 = (idx & 3) * 4;
      int gr = bm + r;
      float4 v = make_float4(0.f, 0.f, 0.f, 0.f);
      if (gr < M) v = *(const float4*)(A + (size_t)gr * K + k0 + c4);
      As[c4 + 0][r] = v.x; As[c4 + 1][r] = v.y;
      As[c4 + 2][r] = v.z; As[c4 + 3][r] = v.w;
    }
    #pragma unroll
    for (int i = 0; i < 2; ++i) {
      int idx = tid + i * 256;
      int r = idx >> 5, c4 = (idx & 31) * 4;
      int gc = bn + c4;
      const float* wp = W + (size_t)(k0 + r) * N + gc;
      float4 v = make_float4(0.f, 0.f, 0.f, 0.f);
      if (gc + 3 < N) v = *(const float4*)wp;
      else {
        if (gc + 0 < N) v.x = wp[0];
        if (gc + 1 < N) v.y = wp[1];
        if (gc + 2 < N) v.z = wp[2];
      }
      *(float4*)&Bsh[r][c4] = v;
    }
    __syncthreads();
    #pragma unroll
    for (int kk = 0; kk < BK; ++kk) {
      float a[8], b[8];
      *(float4*)&a[0] = *(const float4*)&As[kk][ty * 8];
      *(float4*)&a[4] = *(const float4*)&As[kk][ty * 8 + 4];
      *(float4*)&b[0] = *(const float4*)&Bsh[kk][tx * 8];
      *(float4*)&b[4] = *(const float4*)&Bsh[kk][tx * 8 + 4];
      #pragma unroll
      for (int i = 0; i < 8; ++i)
        #pragma unroll
        for (int j = 0; j < 8; ++j)
          acc[i][j] = fmaf(a[i], b[j], acc[i][j]);
    }
    __syncthreads();
  }
  #pragma unroll
  for (int i = 0; i < 8; ++i) {
    int r = bm + ty * 8 + i;
    if (r >= M) continue;
    #pragma unroll
    for (int j = 0; j < 8; ++j) {
      int c = bn + tx * 8 + j;
      if (c >= N) continue;
      float v = acc[i][j] + bias[c];
      if (ACT == 2) v = tanhf(v);
      out[(size_t)r * N + c] = v;
    }
  }
}

// ---------------- patchify: x[B,C,224,224] -> patches[B*196, 768] bf16 ----------------
__global__ __launch_bounds__(256) void patchify_kernel(const float* __restrict__ x,
                                                       __hip_bfloat16* __restrict__ p)
{
  size_t i = (size_t)blockIdx.x * 256 + threadIdx.x;
  constexpr size_t total = (size_t)Bn * NPATCH * 768;
  if (i >= total) return;
  int k = (int)(i % 768);
  size_t m = i / 768;
  int b = (int)(m / NPATCH), pp = (int)(m % NPATCH);
  int py = pp / 14, px = pp % 14;
  int c = k >> 8, ph = (k >> 4) & 15, pw = k & 15;
  p[i] = __float2bfloat16(x[(((size_t)(b * 3 + c)) * 224 + py * 16 + ph) * 224 + px * 16 + pw]);
}

// ---------------- assemble: tokens+cls+pos -> [B,S,D] fp32 ----------------
__global__ __launch_bounds__(256) void assemble_kernel(const float* __restrict__ tok,
                                                       const float* __restrict__ cls,
                                                       const float* __restrict__ pos,
                                                       float* __restrict__ outp)
{
  size_t i = (size_t)blockIdx.x * 256 + threadIdx.x;
  constexpr size_t total = (size_t)Bn * Sn * Dn;
  if (i >= total) return;
  int d = (int)(i % Dn);
  size_t m = i / Dn;
  int s = (int)(m % Sn);
  size_t b = m / Sn;
  float v = (s == 0) ? cls[d] : tok[(b * NPATCH + (s - 1)) * Dn + d];
  outp[i] = v + pos[s * Dn + d];
}

// ---------------- LayerNorm over D=768, one block per row ----------------
template<typename OT>
__global__ __launch_bounds__(256) void ln_kernel(const float* __restrict__ x, size_t xstride,
                                                 const float* __restrict__ g,
                                                 const float* __restrict__ bt,
                                                 OT* __restrict__ out)
{
  const int row = blockIdx.x;
  const int tid = threadIdx.x;
  const float* xr = x + (size_t)row * xstride;
  float v0 = xr[tid], v1 = xr[tid + 256], v2 = xr[tid + 512];
  float s = v0 + v1 + v2;
  float q = v0 * v0 + v1 * v1 + v2 * v2;
  #pragma unroll
  for (int o = 32; o > 0; o >>= 1) { s += __shfl_down(s, o); q += __shfl_down(q, o); }
  __shared__ float sa[4], sb[4];
  int w = tid >> 6, lane = tid & 63;
  if (lane == 0) { sa[w] = s; sb[w] = q; }
  __syncthreads();
  if (tid == 0) {
    float ts = sa[0] + sa[1] + sa[2] + sa[3];
    float tq = sb[0] + sb[1] + sb[2] + sb[3];
    sa[0] = ts; sb[0] = tq;
  }
  __syncthreads();
  s = sa[0]; q = sb[0];
  const float mean = s * (1.f / 768.f);
  const float var  = q * (1.f / 768.f) - mean * mean;
  const float inv  = rsqrtf(var + 1e-5f);
  OT* orow = out + (size_t)row * Dn;
  store_val(orow + tid,       (v0 - mean) * inv * g[tid]       + bt[tid]);
  store_val(orow + tid + 256, (v1 - mean) * inv * g[tid + 256] + bt[tid + 256]);
  store_val(orow + tid + 512, (v2 - mean) * inv * g[tid + 512] + bt[tid + 512]);
}

// ---------------- attention (fp32 compute, bf16 ctx out) ----------------
__global__ __launch_bounds__(256) void attn_kernel(const float* __restrict__ qkv,
                                                   __hip_bfloat16* __restrict__ ctx)
{
  const int bh = blockIdx.x;
  const int b = bh / NHn, h = bh % NHn;
  const int tid = threadIdx.x;
  __shared__ float Ks[64][HDn + 1];
  __shared__ float Vs[64][HDn + 1];

  float qreg[HDn];
  if (tid < Sn) {
    const float* qp = qkv + ((size_t)(b * Sn + tid)) * (3 * Dn) + h * HDn;
    #pragma unroll
    for (int d = 0; d < HDn; ++d) qreg[d] = qp[d];
  }
  float mrun = -1e30f, lsum = 0.f;
  float acc[HDn];
  #pragma unroll
  for (int d = 0; d < HDn; ++d) acc[d] = 0.f;

  const float scale = 0.125f;

  for (int kc = 0; kc < Sn; kc += 64) {
    const int nk = (Sn - kc) < 64 ? (Sn - kc) : 64;
    __syncthreads();
    #pragma unroll
    for (int i = 0; i < 16; ++i) {
      int idx = tid + i * 256;
      int j = idx >> 6, d = idx & 63;
      if (kc + j < Sn) {
        const float* kp = qkv + ((size_t)(b * Sn + kc + j)) * (3 * Dn) + Dn + h * HDn;
        Ks[j][d] = kp[d];
        Vs[j][d] = kp[Dn + d];
      }
    }
    __syncthreads();
    if (tid < Sn) {
      for (int j = 0; j < nk; ++j) {
        float sc = 0.f;
        #pragma unroll
        for (int d = 0; d < HDn; ++d) sc = fmaf(qreg[d], Ks[j][d], sc);
        sc *= scale;
        float mn = fmaxf(mrun, sc);
        float corr = expf(mrun - mn);
        float p = expf(sc - mn);
        lsum = lsum * corr + p;
        #pragma unroll
        for (int d = 0; d < HDn; ++d) acc[d] = fmaf(acc[d], corr, p * Vs[j][d]);
        mrun = mn;
      }
    }
  }
  if (tid < Sn) {
    float r = 1.f / lsum;
    __hip_bfloat16* op = ctx + ((size_t)(b * Sn + tid)) * Dn + h * HDn;
    #pragma unroll
    for (int d = 0; d < HDn; ++d) op[d] = __float2bfloat16(acc[d] * r);
  }
}

// ---------------- host side ----------------
using bf16 = __hip_bfloat16;

static inline void run_convT(const float* W, bf16* Wt, int K, int N, hipStream_t st) {
  convT_kernel<<<dim3(N / 32, K / 32), 256, 0, st>>>(W, Wt, K, N);
}

extern "C" void kernel_launch(void* const* d_in, const int* in_sizes, int n_in,
                              void* d_out, int out_size, void* d_ws, size_t ws_size,
                              hipStream_t stream)
{
  const float* x      = (const float*)d_in[0];
  const float* emb_w  = (const float*)d_in[1];
  const float* emb_b  = (const float*)d_in[2];
  const float* cls    = (const float*)d_in[3];
  const float* pos    = (const float*)d_in[4];
  const float* pre_g  = (const float*)d_in[5];
  const float* pre_b  = (const float*)d_in[6];
  const float* ln1_g  = (const float*)d_in[7];
  const float* ln1_b  = (const float*)d_in[8];
  const float* qkv_w  = (const float*)d_in[9];
  const float* qkv_b  = (const float*)d_in[10];
  const float* proj_w = (const float*)d_in[11];
  const float* proj_b = (const float*)d_in[12];
  const float* ln2_g  = (const float*)d_in[13];
  const float* ln2_b  = (const float*)d_in[14];
  const float* fc1_w  = (const float*)d_in[15];
  const float* fc1_b  = (const float*)d_in[16];
  const float* fc2_w  = (const float*)d_in[17];
  const float* fc2_b  = (const float*)d_in[18];
  const float* post_g = (const float*)d_in[19];
  const float* post_b = (const float*)d_in[20];
  const float* h1_w   = (const float*)d_in[21];
  const float* h1_b   = (const float*)d_in[22];
  const float* h2_w   = (const float*)d_in[23];
  const float* h2_b   = (const float*)d_in[24];
  float* out = (float*)d_out;

  // workspace layout
  const size_t HN = (size_t)Mrows * Dn;          // 4.84M
  float* hbuf = (float*)d_ws;                    // fp32 residual stream [M,D]
  float* qbuf = hbuf + HN;                       // fp32 qkv [M,3D] / tokens
  bf16*  abf1 = (bf16*)(qbuf + (size_t)Mrows * 3 * Dn);   // bf16 [M,D] (y/ctx/patches)
  bf16*  abf2 = abf1 + HN;                       // bf16 [M,DFF] (gelu out / fp32 temps)
  bf16*  wtb  = abf2 + (size_t)Mrows * DFFn;     // bf16 transposed weight (max 2.36M)

  const int gM = (Mrows + 127) / 128;            // 50

  // 1) patchify -> abf1 (bf16 [6272,768])
  patchify_kernel<<<(Bn * NPATCH * Dn) / 256, 256, 0, stream>>>(x, abf1);
  // 2) emb_w^T -> wtb; patch embed GEMM -> qbuf fp32 [6272,768]
  run_convT(emb_w, wtb, Dn, Dn, stream);
  bgemm_kernel<0, false, float><<<dim3(Dn / 128, NPATCH * Bn / 128), 256, 0, stream>>>(
      abf1, wtb, emb_b, nullptr, qbuf, Bn * NPATCH, Dn, Dn);
  // 3) assemble cls+pos -> (float*)abf2; pre-LN -> hbuf
  assemble_kernel<<<(Bn * Sn * Dn) / 256, 256, 0, stream>>>(qbuf, cls, pos, (float*)abf2);
  ln_kernel<float><<<Mrows, 256, 0, stream>>>((float*)abf2, (size_t)Dn, pre_g, pre_b, hbuf);

  for (int l = 0; l < Ln; ++l) {
    const float* g1 = ln1_g + (size_t)l * Dn;
    const float* b1 = ln1_b + (size_t)l * Dn;
    const float* qw = qkv_w + (size_t)l * Dn * 3 * Dn;
    const float* qb = qkv_b + (size_t)l * 3 * Dn;
    const float* pw = proj_w + (size_t)l * Dn * Dn;
    const float* pb = proj_b + (size_t)l * Dn;
    const float* g2 = ln2_g + (size_t)l * Dn;
    const float* b2 = ln2_b + (size_t)l * Dn;
    const float* f1w = fc1_w + (size_t)l * Dn * DFFn;
    const float* f1b = fc1_b + (size_t)l * DFFn;
    const float* f2w = fc2_w + (size_t)l * DFFn * Dn;
    const float* f2b = fc2_b + (size_t)l * Dn;

    // LN1: h -> y (bf16)
    ln_kernel<bf16><<<Mrows, 256, 0, stream>>>(hbuf, (size_t)Dn, g1, b1, abf1);
    // QKV: y @ qw + qb -> qbuf fp32 [M,3D]
    run_convT(qw, wtb, Dn, 3 * Dn, stream);
    bgemm_kernel<0, false, float><<<dim3(3 * Dn / 128, gM), 256, 0, stream>>>(
        abf1, wtb, qb, nullptr, qbuf, Mrows, 3 * Dn, Dn);
    // attention -> abf1 (bf16 ctx)
    attn_kernel<<<Bn * NHn, 256, 0, stream>>>(qbuf, abf1);
    // proj + residual: h += ctx @ pw + pb
    run_convT(pw, wtb, Dn, Dn, stream);
    bgemm_kernel<0, true, float><<<dim3(Dn / 128, gM), 256, 0, stream>>>(
        abf1, wtb, pb, hbuf, hbuf, Mrows, Dn, Dn);
    // LN2: h -> y (bf16)
    ln_kernel<bf16><<<Mrows, 256, 0, stream>>>(hbuf, (size_t)Dn, g2, b2, abf1);
    // fc1 + gelu -> abf2 (bf16 [M,DFF])
    run_convT(f1w, wtb, Dn, DFFn, stream);
    bgemm_kernel<1, false, bf16><<<dim3(DFFn / 128, gM), 256, 0, stream>>>(
        abf1, wtb, f1b, nullptr, abf2, Mrows, DFFn, Dn);
    // fc2 + residual: h += m @ f2w + f2b
    run_convT(f2w, wtb, DFFn, Dn, stream);
    bgemm_kernel<0, true, float><<<dim3(Dn / 128, gM), 256, 0, stream>>>(
        abf2, wtb, f2b, hbuf, hbuf, Mrows, Dn, DFFn);
  }

  // head (fp32 path, M=32): post-LN of h[:,0,:] -> t1; tanh GEMM -> t2; logits
  float* t1 = (float*)abf2;
  float* t2 = t1 + Bn * Dn;
  ln_kernel<float><<<Bn, 256, 0, stream>>>(hbuf, (size_t)Sn * Dn, post_g, post_b, t1);
  gemm_kernel<2><<<dim3((Dn + BN - 1) / BN, 1), 256, 0, stream>>>(
      t1, h1_w, h1_b, t2, Bn, Dn, Dn);
  gemm_kernel<0><<<dim3((OUTn + BN - 1) / BN, 1), 256, 0, stream>>>(
      t2, h2_w, h2_b, out, Bn, OUTn, Dn);
}

// Round 4
// 4480.198 us; speedup vs baseline: 5.3481x; 1.8478x over previous
//
#include <hip/hip_runtime.h>
#include <hip/hip_bf16.h>
#include <math.h>
#include <cstdint>

// ---------------- problem constants ----------------
constexpr int Bn   = 32;
constexpr int Dn   = 768;
constexpr int NHn  = 12;
constexpr int HDn  = 64;
constexpr int Ln   = 12;
constexpr int DFFn = 3072;
constexpr int OUTn = 1000;
constexpr int Sn   = 197;          // 14*14 + 1 tokens
constexpr int Mrows = Bn * Sn;     // 6304
constexpr int NPATCH = 196;

typedef __attribute__((ext_vector_type(8))) short bf16x8;
typedef __attribute__((ext_vector_type(4))) float f32x4;

__device__ inline void store_val(float* p, float v) { *p = v; }
__device__ inline void store_val(__hip_bfloat16* p, float v) { *p = __float2bfloat16(v); }
__device__ inline short f2bs(float f) {
  __hip_bfloat16 h = __float2bfloat16(f);
  return __builtin_bit_cast(short, h);
}

// async global->LDS, 16B per lane; LDS dest = wave-uniform base + lane*16
__device__ inline void gload_lds16(const void* g, void* l) {
  auto gp = (const __attribute__((address_space(1))) unsigned int*)(uintptr_t)g;
  auto lp = (__attribute__((address_space(3))) unsigned int*)(uintptr_t)l;
  __builtin_amdgcn_global_load_lds(gp, lp, 16, 0, 0);
}

// ---------------- bf16 MFMA GEMM ----------------
// C[M,N] = act(A[M,K](bf16) @ Bt[N,K]^T(bf16) + bias) (+res fp32)
template<int ACT, bool RES, typename OT>   // ACT: 0 none, 1 gelu(exact)
__global__ __launch_bounds__(256) void bgemm_kernel(
    const __hip_bfloat16* __restrict__ A,
    const __hip_bfloat16* __restrict__ Bt,
    const float* __restrict__ bias,
    const float* __restrict__ res,
    OT* __restrict__ out, int M, int N, int K)
{
  __shared__ __hip_bfloat16 As[128 * 32];   // 8 KB
  __shared__ __hip_bfloat16 Bs[128 * 32];   // 8 KB
  const int tid  = threadIdx.x;
  const int w    = tid >> 6, lane = tid & 63;
  const int wm   = w >> 1,   wn   = w & 1;
  const int bm   = blockIdx.y * 128, bn = blockIdx.x * 128;
  const int kg   = lane >> 4, fr = lane & 15;

  f32x4 acc[4][4];
  #pragma unroll
  for (int i = 0; i < 4; ++i)
    #pragma unroll
    for (int j = 0; j < 4; ++j) acc[i][j] = (f32x4)(0.f);

  for (int k0 = 0; k0 < K; k0 += 32) {
    #pragma unroll
    for (int i = 0; i < 2; ++i) {
      const int obase = w * 2048 + i * 1024;       // wave-uniform LDS byte base
      const int o  = obase + lane * 16;
      const int r  = o >> 6;
      const int ks = (((o >> 4) & 3) ^ (r & 3)) * 8;
      {
        int gr = bm + r; if (gr >= M) gr = M - 1;
        gload_lds16(A + (size_t)gr * K + k0 + ks, (char*)As + obase);
      }
      {
        const int gc = bn + r;
        gload_lds16(Bt + (size_t)gc * K + k0 + ks, (char*)Bs + obase);
      }
    }
    __syncthreads();

    bf16x8 af[4], bfv[4];
    #pragma unroll
    for (int t = 0; t < 4; ++t) {
      const int r = wm * 64 + t * 16 + fr;
      af[t]  = *(const bf16x8*)((const char*)As + r * 64 + ((kg ^ (r & 3)) << 4));
      const int c = wn * 64 + t * 16 + fr;
      bfv[t] = *(const bf16x8*)((const char*)Bs + c * 64 + ((kg ^ (c & 3)) << 4));
    }
    #pragma unroll
    for (int mt = 0; mt < 4; ++mt)
      #pragma unroll
      for (int nt = 0; nt < 4; ++nt)
        acc[mt][nt] = __builtin_amdgcn_mfma_f32_16x16x32_bf16(af[mt], bfv[nt], acc[mt][nt], 0, 0, 0);
    __syncthreads();
  }

  #pragma unroll
  for (int nt = 0; nt < 4; ++nt) {
    const int cb = bn + wn * 64 + nt * 16 + fr;
    const float bs = bias[cb];
    #pragma unroll
    for (int mt = 0; mt < 4; ++mt) {
      #pragma unroll
      for (int j = 0; j < 4; ++j) {
        const int rb = bm + wm * 64 + mt * 16 + kg * 4 + j;
        if (rb >= M) continue;
        float v = acc[mt][nt][j] + bs;
        if (ACT == 1) v = 0.5f * v * (1.f + erff(v * 0.70710678118654752f));
        if (RES) v += res[(size_t)rb * N + cb];
        store_val(out + (size_t)rb * N + cb, v);
      }
    }
  }
}

// ---------------- transpose-convert: W[K,N] fp32 -> Wt[N,K] bf16 ----------------
__global__ __launch_bounds__(256) void convT_kernel(const float* __restrict__ W,
                                                    __hip_bfloat16* __restrict__ Wt,
                                                    int K, int N)
{
  __shared__ float t[32][33];
  const int k0 = blockIdx.y * 32, n0 = blockIdx.x * 32;
  const int r  = threadIdx.x >> 3, c4 = (threadIdx.x & 7) * 4;
  float4 v = *(const float4*)(W + (size_t)(k0 + r) * N + n0 + c4);
  t[r][c4 + 0] = v.x; t[r][c4 + 1] = v.y; t[r][c4 + 2] = v.z; t[r][c4 + 3] = v.w;
  __syncthreads();
  __hip_bfloat16* o = Wt + (size_t)(n0 + r) * K + k0 + c4;
  o[0] = __float2bfloat16(t[c4 + 0][r]);
  o[1] = __float2bfloat16(t[c4 + 1][r]);
  o[2] = __float2bfloat16(t[c4 + 2][r]);
  o[3] = __float2bfloat16(t[c4 + 3][r]);
}

// ---------------- fp32 GEMM (head only, M=32) ----------------
constexpr int BM = 128, BN = 128, BK = 16;
template<int ACT>   // 0 none, 2 tanh
__global__ __launch_bounds__(256) void gemm_kernel(
    const float* __restrict__ A, const float* __restrict__ W,
    const float* __restrict__ bias,
    float* __restrict__ out, int M, int N, int K)
{
  __shared__ __align__(16) float As[BK][BM + 8];
  __shared__ __align__(16) float Bsh[BK][BN + 8];
  const int tid = threadIdx.x;
  const int tx = tid & 15, ty = tid >> 4;
  const int bm = blockIdx.y * BM;
  const int bn = blockIdx.x * BN;

  float acc[8][8];
  #pragma unroll
  for (int i = 0; i < 8; ++i)
    #pragma unroll
    for (int j = 0; j < 8; ++j) acc[i][j] = 0.f;

  for (int k0 = 0; k0 < K; k0 += BK) {
    #pragma unroll
    for (int i = 0; i < 2; ++i) {
      int idx = tid + i * 256;
      int r = idx >> 2, c4 = (idx & 3) * 4;
      int gr = bm + r;
      float4 v = make_float4(0.f, 0.f, 0.f, 0.f);
      if (gr < M) v = *(const float4*)(A + (size_t)gr * K + k0 + c4);
      As[c4 + 0][r] = v.x; As[c4 + 1][r] = v.y;
      As[c4 + 2][r] = v.z; As[c4 + 3][r] = v.w;
    }
    #pragma unroll
    for (int i = 0; i < 2; ++i) {
      int idx = tid + i * 256;
      int r = idx >> 5, c4 = (idx & 31) * 4;
      int gc = bn + c4;
      const float* wp = W + (size_t)(k0 + r) * N + gc;
      float4 v = make_float4(0.f, 0.f, 0.f, 0.f);
      if (gc + 3 < N) v = *(const float4*)wp;
      else {
        if (gc + 0 < N) v.x = wp[0];
        if (gc + 1 < N) v.y = wp[1];
        if (gc + 2 < N) v.z = wp[2];
      }
      *(float4*)&Bsh[r][c4] = v;
    }
    __syncthreads();
    #pragma unroll
    for (int kk = 0; kk < BK; ++kk) {
      float a[8], b[8];
      *(float4*)&a[0] = *(const float4*)&As[kk][ty * 8];
      *(float4*)&a[4] = *(const float4*)&As[kk][ty * 8 + 4];
      *(float4*)&b[0] = *(const float4*)&Bsh[kk][tx * 8];
      *(float4*)&b[4] = *(const float4*)&Bsh[kk][tx * 8 + 4];
      #pragma unroll
      for (int i = 0; i < 8; ++i)
        #pragma unroll
        for (int j = 0; j < 8; ++j)
          acc[i][j] = fmaf(a[i], b[j], acc[i][j]);
    }
    __syncthreads();
  }
  #pragma unroll
  for (int i = 0; i < 8; ++i) {
    int r = bm + ty * 8 + i;
    if (r >= M) continue;
    #pragma unroll
    for (int j = 0; j < 8; ++j) {
      int c = bn + tx * 8 + j;
      if (c >= N) continue;
      float v = acc[i][j] + bias[c];
      if (ACT == 2) v = tanhf(v);
      out[(size_t)r * N + c] = v;
    }
  }
}

// ---------------- patchify: x[B,C,224,224] -> patches[B*196, 768] bf16 ----------------
__global__ __launch_bounds__(256) void patchify_kernel(const float* __restrict__ x,
                                                       __hip_bfloat16* __restrict__ p)
{
  size_t i = (size_t)blockIdx.x * 256 + threadIdx.x;
  constexpr size_t total = (size_t)Bn * NPATCH * 768;
  if (i >= total) return;
  int k = (int)(i % 768);
  size_t m = i / 768;
  int b = (int)(m / NPATCH), pp = (int)(m % NPATCH);
  int py = pp / 14, px = pp % 14;
  int c = k >> 8, ph = (k >> 4) & 15, pw = k & 15;
  p[i] = __float2bfloat16(x[(((size_t)(b * 3 + c)) * 224 + py * 16 + ph) * 224 + px * 16 + pw]);
}

// ---------------- assemble: tokens+cls+pos -> [B,S,D] fp32 ----------------
__global__ __launch_bounds__(256) void assemble_kernel(const float* __restrict__ tok,
                                                       const float* __restrict__ cls,
                                                       const float* __restrict__ pos,
                                                       float* __restrict__ outp)
{
  size_t i = (size_t)blockIdx.x * 256 + threadIdx.x;
  constexpr size_t total = (size_t)Bn * Sn * Dn;
  if (i >= total) return;
  int d = (int)(i % Dn);
  size_t m = i / Dn;
  int s = (int)(m % Sn);
  size_t b = m / Sn;
  float v = (s == 0) ? cls[d] : tok[(b * NPATCH + (s - 1)) * Dn + d];
  outp[i] = v + pos[s * Dn + d];
}

// ---------------- LayerNorm over D=768, one block per row ----------------
template<typename OT>
__global__ __launch_bounds__(256) void ln_kernel(const float* __restrict__ x, size_t xstride,
                                                 const float* __restrict__ g,
                                                 const float* __restrict__ bt,
                                                 OT* __restrict__ out)
{
  const int row = blockIdx.x;
  const int tid = threadIdx.x;
  const float* xr = x + (size_t)row * xstride;
  float v0 = xr[tid], v1 = xr[tid + 256], v2 = xr[tid + 512];
  float s = v0 + v1 + v2;
  float q = v0 * v0 + v1 * v1 + v2 * v2;
  #pragma unroll
  for (int o = 32; o > 0; o >>= 1) { s += __shfl_down(s, o); q += __shfl_down(q, o); }
  __shared__ float sa[4], sb[4];
  int w = tid >> 6, lane = tid & 63;
  if (lane == 0) { sa[w] = s; sb[w] = q; }
  __syncthreads();
  if (tid == 0) {
    float ts = sa[0] + sa[1] + sa[2] + sa[3];
    float tq = sb[0] + sb[1] + sb[2] + sb[3];
    sa[0] = ts; sb[0] = tq;
  }
  __syncthreads();
  s = sa[0]; q = sb[0];
  const float mean = s * (1.f / 768.f);
  const float var  = q * (1.f / 768.f) - mean * mean;
  const float inv  = rsqrtf(var + 1e-5f);
  OT* orow = out + (size_t)row * Dn;
  store_val(orow + tid,       (v0 - mean) * inv * g[tid]       + bt[tid]);
  store_val(orow + tid + 256, (v1 - mean) * inv * g[tid + 256] + bt[tid + 256]);
  store_val(orow + tid + 512, (v2 - mean) * inv * g[tid + 512] + bt[tid + 512]);
}

// ---------------- MFMA flash attention ----------------
// Block = (b, h); 4 waves, each owns 64 Q rows. qkv bf16 [B*S, 2304].
// K in LDS [224][64] slot-XOR-swizzled; V^T in LDS [64][232-stride];
// P round-trips through per-wave 4KB swizzled LDS tile.
constexpr int SP2 = 224;
constexpr int VTS = 232;
__global__ __launch_bounds__(256) void attn_mfma_kernel(
    const __hip_bfloat16* __restrict__ qkv, __hip_bfloat16* __restrict__ ctx)
{
  const int b = blockIdx.x / NHn, h = blockIdx.x % NHn;
  const int tid = threadIdx.x;
  const int w = tid >> 6, lane = tid & 63;
  const int kg = lane >> 4, fr = lane & 15;

  __shared__ short Kl[SP2 * 64];       // 28672 B
  __shared__ short Vt[64 * VTS];       // 29696 B
  __shared__ short Pl[4 * 2048];       // 16384 B, per-wave [64][32]

  const size_t rstr = 3 * (size_t)Dn;  // 2304
  const __hip_bfloat16* base = qkv + (size_t)b * Sn * rstr;

  // ---- stage K: slot i: r=i>>3 (key), s=i&7; content = K[r][(s^(r&7))*8..+8) ----
  #pragma unroll
  for (int it = 0; it < 7; ++it) {
    const int i = it * 256 + tid;
    const int r = i >> 3, s = i & 7;
    const int rr = r < Sn ? r : Sn - 1;
    gload_lds16(base + (size_t)rr * rstr + Dn + h * HDn + ((s ^ (r & 7)) << 3),
                (char*)Kl + it * 4096 + w * 1024);
  }
  // ---- stage V^T (reg->LDS transpose) ----
  #pragma unroll
  for (int it = 0; it < 7; ++it) {
    const int i = it * 256 + tid;
    const int key = i >> 3, d0 = (i & 7) * 8;
    const int rr = key < Sn ? key : Sn - 1;
    bf16x8 v = *(const bf16x8*)(base + (size_t)rr * rstr + 2 * Dn + h * HDn + d0);
    #pragma unroll
    for (int e = 0; e < 8; ++e) Vt[(d0 + e) * VTS + key] = v[e];
  }
  // ---- Q fragments in registers ----
  const int qw = w * 64;
  bf16x8 qf[4][2];
  #pragma unroll
  for (int qt = 0; qt < 4; ++qt)
    #pragma unroll
    for (int kk = 0; kk < 2; ++kk) {
      int q = qw + qt * 16 + fr; if (q >= Sn) q = Sn - 1;
      qf[qt][kk] = *(const bf16x8*)(base + (size_t)q * rstr + h * HDn + kk * 32 + kg * 8);
    }
  __syncthreads();

  float mold[4][4], lsum[4][4];
  f32x4 cacc[4][4];
  #pragma unroll
  for (int qt = 0; qt < 4; ++qt)
    #pragma unroll
    for (int j = 0; j < 4; ++j) {
      mold[qt][j] = -1e30f; lsum[qt][j] = 0.f;
      cacc[qt][j] = (f32x4)(0.f);
    }
  const float scale = 0.125f;

  for (int kc = 0; kc < SP2; kc += 32) {
    // ---- scores: D[q, key] ----
    f32x4 sacc[4][2];
    #pragma unroll
    for (int qt = 0; qt < 4; ++qt) { sacc[qt][0] = (f32x4)(0.f); sacc[qt][1] = (f32x4)(0.f); }
    #pragma unroll
    for (int nt = 0; nt < 2; ++nt) {
      const int key = kc + nt * 16 + fr;
      const bf16x8 kf0 = *(const bf16x8*)((const char*)Kl + key * 128 + ((kg ^ (key & 7)) << 4));
      const bf16x8 kf1 = *(const bf16x8*)((const char*)Kl + key * 128 + (((4 + kg) ^ (key & 7)) << 4));
      #pragma unroll
      for (int qt = 0; qt < 4; ++qt) {
        sacc[qt][nt] = __builtin_amdgcn_mfma_f32_16x16x32_bf16(qf[qt][0], kf0, sacc[qt][nt], 0, 0, 0);
        sacc[qt][nt] = __builtin_amdgcn_mfma_f32_16x16x32_bf16(qf[qt][1], kf1, sacc[qt][nt], 0, 0, 0);
      }
    }
    // scale + additive key-mask
    const float madd0 = (kc + fr < Sn) ? 0.f : -3e38f;
    const float madd1 = (kc + 16 + fr < Sn) ? 0.f : -3e38f;
    #pragma unroll
    for (int qt = 0; qt < 4; ++qt) {
      sacc[qt][0] = sacc[qt][0] * scale + (f32x4)(madd0);
      sacc[qt][1] = sacc[qt][1] * scale + (f32x4)(madd1);
    }
    // ---- online softmax (reduce over the 16 fr-lanes = keys) ----
    #pragma unroll
    for (int qt = 0; qt < 4; ++qt) {
      #pragma unroll
      for (int j = 0; j < 4; ++j) {
        float t = fmaxf(sacc[qt][0][j], sacc[qt][1][j]);
        t = fmaxf(t, __shfl_xor(t, 1));
        t = fmaxf(t, __shfl_xor(t, 2));
        t = fmaxf(t, __shfl_xor(t, 4));
        t = fmaxf(t, __shfl_xor(t, 8));
        const float mn = fmaxf(mold[qt][j], t);
        const float corr = __expf(mold[qt][j] - mn);
        mold[qt][j] = mn;
        const float p0 = __expf(sacc[qt][0][j] - mn);
        const float p1 = __expf(sacc[qt][1][j] - mn);
        sacc[qt][0][j] = p0; sacc[qt][1][j] = p1;
        float ps = p0 + p1;
        ps += __shfl_xor(ps, 1); ps += __shfl_xor(ps, 2);
        ps += __shfl_xor(ps, 4); ps += __shfl_xor(ps, 8);
        lsum[qt][j] = lsum[qt][j] * corr + ps;
        #pragma unroll
        for (int ht = 0; ht < 4; ++ht) cacc[qt][ht][j] *= corr;
      }
      // write P tile to wave-private LDS (bf16, slot-swizzled)
      #pragma unroll
      for (int nt = 0; nt < 2; ++nt) {
        const int c = nt * 16 + fr;
        #pragma unroll
        for (int j = 0; j < 4; ++j) {
          const int r = qt * 16 + kg * 4 + j;
          Pl[w * 2048 + r * 32 + (((c >> 3) ^ (r & 3)) << 3) + (c & 7)] = f2bs(sacc[qt][nt][j]);
        }
      }
    }
    // ---- PV: ctx[q, head] += P[q, key] @ V[key, head] ----
    bf16x8 vf[4];
    #pragma unroll
    for (int ht = 0; ht < 4; ++ht)
      vf[ht] = *(const bf16x8*)(Vt + (ht * 16 + fr) * VTS + kc + kg * 8);
    #pragma unroll
    for (int qt = 0; qt < 4; ++qt) {
      const int r = qt * 16 + fr;
      const bf16x8 pf = *(const bf16x8*)(Pl + w * 2048 + r * 32 + ((kg ^ (r & 3)) << 3));
      #pragma unroll
      for (int ht = 0; ht < 4; ++ht)
        cacc[qt][ht] = __builtin_amdgcn_mfma_f32_16x16x32_bf16(pf, vf[ht], cacc[qt][ht], 0, 0, 0);
    }
  }
  // ---- epilogue ----
  __hip_bfloat16* cb = ctx + (size_t)b * Sn * Dn + h * HDn;
  #pragma unroll
  for (int qt = 0; qt < 4; ++qt)
    #pragma unroll
    for (int j = 0; j < 4; ++j) {
      const int q = qw + qt * 16 + kg * 4 + j;
      if (q < Sn) {
        const float inv = 1.f / lsum[qt][j];
        #pragma unroll
        for (int ht = 0; ht < 4; ++ht)
          cb[(size_t)q * Dn + ht * 16 + fr] = __float2bfloat16(cacc[qt][ht][j] * inv);
      }
    }
}

// ---------------- host side ----------------
using bf16 = __hip_bfloat16;

static inline void run_convT(const float* W, bf16* Wt, int K, int N, hipStream_t st) {
  convT_kernel<<<dim3(N / 32, K / 32), 256, 0, st>>>(W, Wt, K, N);
}

extern "C" void kernel_launch(void* const* d_in, const int* in_sizes, int n_in,
                              void* d_out, int out_size, void* d_ws, size_t ws_size,
                              hipStream_t stream)
{
  const float* x      = (const float*)d_in[0];
  const float* emb_w  = (const float*)d_in[1];
  const float* emb_b  = (const float*)d_in[2];
  const float* cls    = (const float*)d_in[3];
  const float* pos    = (const float*)d_in[4];
  const float* pre_g  = (const float*)d_in[5];
  const float* pre_b  = (const float*)d_in[6];
  const float* ln1_g  = (const float*)d_in[7];
  const float* ln1_b  = (const float*)d_in[8];
  const float* qkv_w  = (const float*)d_in[9];
  const float* qkv_b  = (const float*)d_in[10];
  const float* proj_w = (const float*)d_in[11];
  const float* proj_b = (const float*)d_in[12];
  const float* ln2_g  = (const float*)d_in[13];
  const float* ln2_b  = (const float*)d_in[14];
  const float* fc1_w  = (const float*)d_in[15];
  const float* fc1_b  = (const float*)d_in[16];
  const float* fc2_w  = (const float*)d_in[17];
  const float* fc2_b  = (const float*)d_in[18];
  const float* post_g = (const float*)d_in[19];
  const float* post_b = (const float*)d_in[20];
  const float* h1_w   = (const float*)d_in[21];
  const float* h1_b   = (const float*)d_in[22];
  const float* h2_w   = (const float*)d_in[23];
  const float* h2_b   = (const float*)d_in[24];
  float* out = (float*)d_out;

  // workspace layout
  const size_t HN = (size_t)Mrows * Dn;
  float* hbuf = (float*)d_ws;                         // fp32 residual [M,768]
  bf16*  qkvb = (bf16*)(hbuf + HN);                   // bf16 [M,2304]; also fp32 [M,768] staging
  bf16*  abf1 = qkvb + (size_t)Mrows * 3 * Dn;        // bf16 [M,768]
  bf16*  abf2 = abf1 + HN;                            // bf16 [M,3072]; also fp32 [6272,768]
  bf16*  wtb  = abf2 + (size_t)Mrows * DFFn;          // bf16 transposed weight (max 2304x768)

  const int gM = (Mrows + 127) / 128;                 // 50

  // 1) patchify -> abf1 (bf16)
  patchify_kernel<<<(Bn * NPATCH * Dn) / 256, 256, 0, stream>>>(x, abf1);
  // 2) patch embed GEMM -> (float*)abf2
  run_convT(emb_w, wtb, Dn, Dn, stream);
  bgemm_kernel<0, false, float><<<dim3(Dn / 128, NPATCH * Bn / 128), 256, 0, stream>>>(
      abf1, wtb, emb_b, nullptr, (float*)abf2, Bn * NPATCH, Dn, Dn);
  // 3) assemble cls+pos -> (float*)qkvb; pre-LN -> hbuf
  assemble_kernel<<<(Bn * Sn * Dn) / 256, 256, 0, stream>>>((float*)abf2, cls, pos, (float*)qkvb);
  ln_kernel<float><<<Mrows, 256, 0, stream>>>((float*)qkvb, (size_t)Dn, pre_g, pre_b, hbuf);

  for (int l = 0; l < Ln; ++l) {
    const float* g1 = ln1_g + (size_t)l * Dn;
    const float* b1 = ln1_b + (size_t)l * Dn;
    const float* qw = qkv_w + (size_t)l * Dn * 3 * Dn;
    const float* qb = qkv_b + (size_t)l * 3 * Dn;
    const float* pw = proj_w + (size_t)l * Dn * Dn;
    const float* pb = proj_b + (size_t)l * Dn;
    const float* g2 = ln2_g + (size_t)l * Dn;
    const float* b2 = ln2_b + (size_t)l * Dn;
    const float* f1w = fc1_w + (size_t)l * Dn * DFFn;
    const float* f1b = fc1_b + (size_t)l * DFFn;
    const float* f2w = fc2_w + (size_t)l * DFFn * Dn;
    const float* f2b = fc2_b + (size_t)l * Dn;

    // LN1: h -> y (bf16)
    ln_kernel<bf16><<<Mrows, 256, 0, stream>>>(hbuf, (size_t)Dn, g1, b1, abf1);
    // QKV: y @ qw + qb -> qkvb (bf16 [M,3D])
    run_convT(qw, wtb, Dn, 3 * Dn, stream);
    bgemm_kernel<0, false, bf16><<<dim3(3 * Dn / 128, gM), 256, 0, stream>>>(
        abf1, wtb, qb, nullptr, qkvb, Mrows, 3 * Dn, Dn);
    // attention -> abf1 (bf16 ctx)
    attn_mfma_kernel<<<Bn * NHn, 256, 0, stream>>>(qkvb, abf1);
    // proj + residual: h += ctx @ pw + pb
    run_convT(pw, wtb, Dn, Dn, stream);
    bgemm_kernel<0, true, float><<<dim3(Dn / 128, gM), 256, 0, stream>>>(
        abf1, wtb, pb, hbuf, hbuf, Mrows, Dn, Dn);
    // LN2: h -> y (bf16)
    ln_kernel<bf16><<<Mrows, 256, 0, stream>>>(hbuf, (size_t)Dn, g2, b2, abf1);
    // fc1 + gelu -> abf2 (bf16 [M,DFF])
    run_convT(f1w, wtb, Dn, DFFn, stream);
    bgemm_kernel<1, false, bf16><<<dim3(DFFn / 128, gM), 256, 0, stream>>>(
        abf1, wtb, f1b, nullptr, abf2, Mrows, DFFn, Dn);
    // fc2 + residual: h += m @ f2w + f2b
    run_convT(f2w, wtb, DFFn, Dn, stream);
    bgemm_kernel<0, true, float><<<dim3(Dn / 128, gM), 256, 0, stream>>>(
        abf2, wtb, f2b, hbuf, hbuf, Mrows, Dn, DFFn);
  }

  // head (fp32 path, M=32)
  float* t1 = (float*)abf2;
  float* t2 = t1 + Bn * Dn;
  ln_kernel<float><<<Bn, 256, 0, stream>>>(hbuf, (size_t)Sn * Dn, post_g, post_b, t1);
  gemm_kernel<2><<<dim3((Dn + BN - 1) / BN, 1), 256, 0, stream>>>(
      t1, h1_w, h1_b, t2, Bn, Dn, Dn);
  gemm_kernel<0><<<dim3((OUTn + BN - 1) / BN, 1), 256, 0, stream>>>(
      t2, h2_w, h2_b, out, Bn, OUTn, Dn);
}

// Round 5
// 4233.972 us; speedup vs baseline: 5.6591x; 1.0582x over previous
//
#include <hip/hip_runtime.h>
#include <hip/hip_bf16.h>
#include <math.h>
#include <cstdint>

// ---------------- problem constants ----------------
constexpr int Bn   = 32;
constexpr int Dn   = 768;
constexpr int NHn  = 12;
constexpr int HDn  = 64;
constexpr int Ln   = 12;
constexpr int DFFn = 3072;
constexpr int OUTn = 1000;
constexpr int Sn   = 197;          // 14*14 + 1 tokens
constexpr int Mrows = Bn * Sn;     // 6304
constexpr int NPATCH = 196;

typedef __attribute__((ext_vector_type(8))) short bf16x8;
typedef __attribute__((ext_vector_type(4))) float f32x4;

__device__ inline void store_val(float* p, float v) { *p = v; }
__device__ inline void store_val(__hip_bfloat16* p, float v) { *p = __float2bfloat16(v); }
__device__ inline short f2bs(float f) {
  __hip_bfloat16 h = __float2bfloat16(f);
  return __builtin_bit_cast(short, h);
}

// async global->LDS, 16B per lane; LDS dest = wave-uniform base + lane*16
__device__ inline void gload_lds16(const void* g, void* l) {
  auto gp = (const __attribute__((address_space(1))) unsigned int*)(uintptr_t)g;
  auto lp = (__attribute__((address_space(3))) unsigned int*)(uintptr_t)l;
  __builtin_amdgcn_global_load_lds(gp, lp, 16, 0, 0);
}

// ---------------- bf16 MFMA GEMM ----------------
// C[M,N] = act(A[M,K](bf16) @ Bt[N,K]^T(bf16) + bias) (+res fp32)
template<int ACT, bool RES, typename OT>   // ACT: 0 none, 1 gelu(exact)
__global__ __launch_bounds__(256) void bgemm_kernel(
    const __hip_bfloat16* __restrict__ A,
    const __hip_bfloat16* __restrict__ Bt,
    const float* __restrict__ bias,
    const float* __restrict__ res,
    OT* __restrict__ out, int M, int N, int K)
{
  __shared__ __hip_bfloat16 As[128 * 32];   // 8 KB
  __shared__ __hip_bfloat16 Bs[128 * 32];   // 8 KB
  const int tid  = threadIdx.x;
  const int w    = tid >> 6, lane = tid & 63;
  const int wm   = w >> 1,   wn   = w & 1;
  const int bm   = blockIdx.y * 128, bn = blockIdx.x * 128;
  const int kg   = lane >> 4, fr = lane & 15;

  f32x4 acc[4][4];
  #pragma unroll
  for (int i = 0; i < 4; ++i)
    #pragma unroll
    for (int j = 0; j < 4; ++j) acc[i][j] = (f32x4)(0.f);

  for (int k0 = 0; k0 < K; k0 += 32) {
    #pragma unroll
    for (int i = 0; i < 2; ++i) {
      const int obase = w * 2048 + i * 1024;       // wave-uniform LDS byte base
      const int o  = obase + lane * 16;
      const int r  = o >> 6;
      const int ks = (((o >> 4) & 3) ^ (r & 3)) * 8;
      {
        int gr = bm + r; if (gr >= M) gr = M - 1;
        gload_lds16(A + (size_t)gr * K + k0 + ks, (char*)As + obase);
      }
      {
        const int gc = bn + r;
        gload_lds16(Bt + (size_t)gc * K + k0 + ks, (char*)Bs + obase);
      }
    }
    __syncthreads();

    bf16x8 af[4], bfv[4];
    #pragma unroll
    for (int t = 0; t < 4; ++t) {
      const int r = wm * 64 + t * 16 + fr;
      af[t]  = *(const bf16x8*)((const char*)As + r * 64 + ((kg ^ (r & 3)) << 4));
      const int c = wn * 64 + t * 16 + fr;
      bfv[t] = *(const bf16x8*)((const char*)Bs + c * 64 + ((kg ^ (c & 3)) << 4));
    }
    #pragma unroll
    for (int mt = 0; mt < 4; ++mt)
      #pragma unroll
      for (int nt = 0; nt < 4; ++nt)
        acc[mt][nt] = __builtin_amdgcn_mfma_f32_16x16x32_bf16(af[mt], bfv[nt], acc[mt][nt], 0, 0, 0);
    __syncthreads();
  }

  #pragma unroll
  for (int nt = 0; nt < 4; ++nt) {
    const int cb = bn + wn * 64 + nt * 16 + fr;
    const float bs = bias[cb];
    #pragma unroll
    for (int mt = 0; mt < 4; ++mt) {
      #pragma unroll
      for (int j = 0; j < 4; ++j) {
        const int rb = bm + wm * 64 + mt * 16 + kg * 4 + j;
        if (rb >= M) continue;
        float v = acc[mt][nt][j] + bs;
        if (ACT == 1) v = 0.5f * v * (1.f + erff(v * 0.70710678118654752f));
        if (RES) v += res[(size_t)rb * N + cb];
        store_val(out + (size_t)rb * N + cb, v);
      }
    }
  }
}

// ---------------- transpose-convert: W[z][K,N] fp32 -> Wt[z][N,K] bf16 (guarded) ----------------
__global__ __launch_bounds__(256) void convT_kernel(const float* __restrict__ W,
                                                    __hip_bfloat16* __restrict__ Wt,
                                                    int K, int N)
{
  const size_t lw = (size_t)K * N;
  const float* Wb = W + blockIdx.z * lw;
  __hip_bfloat16* Wo = Wt + blockIdx.z * lw;
  __shared__ float t[32][33];
  const int k0 = blockIdx.y * 32, n0 = blockIdx.x * 32;
  const int r  = threadIdx.x >> 3, c4 = (threadIdx.x & 7) * 4;
  const float* wp = Wb + (size_t)(k0 + r) * N + n0 + c4;
  float4 v = make_float4(0.f, 0.f, 0.f, 0.f);
  if (n0 + c4 + 3 < N) v = *(const float4*)wp;
  else {
    if (n0 + c4 + 0 < N) v.x = wp[0];
    if (n0 + c4 + 1 < N) v.y = wp[1];
    if (n0 + c4 + 2 < N) v.z = wp[2];
  }
  t[r][c4 + 0] = v.x; t[r][c4 + 1] = v.y; t[r][c4 + 2] = v.z; t[r][c4 + 3] = v.w;
  __syncthreads();
  const int n = n0 + r;
  if (n < N) {
    __hip_bfloat16* o = Wo + (size_t)n * K + k0 + c4;
    o[0] = __float2bfloat16(t[c4 + 0][r]);
    o[1] = __float2bfloat16(t[c4 + 1][r]);
    o[2] = __float2bfloat16(t[c4 + 2][r]);
    o[3] = __float2bfloat16(t[c4 + 3][r]);
  }
}

// ---------------- head GEMV: out[32,N] = act(A[32,K] @ Wt[N,K]^T + bias) ----------------
// One wave per output element; coalesced A fp32 + Wt bf16 reads; shfl reduce.
template<int ACT>   // 0 none, 2 tanh
__global__ __launch_bounds__(256) void hgemv_kernel(
    const float* __restrict__ A, const __hip_bfloat16* __restrict__ Wt,
    const float* __restrict__ bias, float* __restrict__ out, int N, int K)
{
  const int w = threadIdx.x >> 6, lane = threadIdx.x & 63;
  const int e = blockIdx.x * 4 + w;
  const int m = e & 31, n = e >> 5;
  if (n >= N) return;
  const float* a = A + (size_t)m * K;
  const __hip_bfloat16* wr = Wt + (size_t)n * K;
  float s = 0.f;
  for (int k = lane; k < K; k += 64)
    s = fmaf(a[k], __bfloat162float(wr[k]), s);
  #pragma unroll
  for (int o = 32; o > 0; o >>= 1) s += __shfl_xor(s, o);
  if (lane == 0) {
    float v = s + bias[n];
    if (ACT == 2) v = tanhf(v);
    out[(size_t)m * N + n] = v;
  }
}

// ---------------- patchify: x[B,C,224,224] -> patches[B*196, 768] bf16 ----------------
__global__ __launch_bounds__(256) void patchify_kernel(const float* __restrict__ x,
                                                       __hip_bfloat16* __restrict__ p)
{
  size_t i = (size_t)blockIdx.x * 256 + threadIdx.x;
  constexpr size_t total = (size_t)Bn * NPATCH * 768;
  if (i >= total) return;
  int k = (int)(i % 768);
  size_t m = i / 768;
  int b = (int)(m / NPATCH), pp = (int)(m % NPATCH);
  int py = pp / 14, px = pp % 14;
  int c = k >> 8, ph = (k >> 4) & 15, pw = k & 15;
  p[i] = __float2bfloat16(x[(((size_t)(b * 3 + c)) * 224 + py * 16 + ph) * 224 + px * 16 + pw]);
}

// ---------------- assemble: tokens+cls+pos -> [B,S,D] fp32 ----------------
__global__ __launch_bounds__(256) void assemble_kernel(const float* __restrict__ tok,
                                                       const float* __restrict__ cls,
                                                       const float* __restrict__ pos,
                                                       float* __restrict__ outp)
{
  size_t i = (size_t)blockIdx.x * 256 + threadIdx.x;
  constexpr size_t total = (size_t)Bn * Sn * Dn;
  if (i >= total) return;
  int d = (int)(i % Dn);
  size_t m = i / Dn;
  int s = (int)(m % Sn);
  size_t b = m / Sn;
  float v = (s == 0) ? cls[d] : tok[(b * NPATCH + (s - 1)) * Dn + d];
  outp[i] = v + pos[s * Dn + d];
}

// ---------------- LayerNorm over D=768, one block per row ----------------
template<typename OT>
__global__ __launch_bounds__(256) void ln_kernel(const float* __restrict__ x, size_t xstride,
                                                 const float* __restrict__ g,
                                                 const float* __restrict__ bt,
                                                 OT* __restrict__ out)
{
  const int row = blockIdx.x;
  const int tid = threadIdx.x;
  const float* xr = x + (size_t)row * xstride;
  float v0 = xr[tid], v1 = xr[tid + 256], v2 = xr[tid + 512];
  float s = v0 + v1 + v2;
  float q = v0 * v0 + v1 * v1 + v2 * v2;
  #pragma unroll
  for (int o = 32; o > 0; o >>= 1) { s += __shfl_down(s, o); q += __shfl_down(q, o); }
  __shared__ float sa[4], sb[4];
  int w = tid >> 6, lane = tid & 63;
  if (lane == 0) { sa[w] = s; sb[w] = q; }
  __syncthreads();
  if (tid == 0) {
    float ts = sa[0] + sa[1] + sa[2] + sa[3];
    float tq = sb[0] + sb[1] + sb[2] + sb[3];
    sa[0] = ts; sb[0] = tq;
  }
  __syncthreads();
  s = sa[0]; q = sb[0];
  const float mean = s * (1.f / 768.f);
  const float var  = q * (1.f / 768.f) - mean * mean;
  const float inv  = rsqrtf(var + 1e-5f);
  OT* orow = out + (size_t)row * Dn;
  store_val(orow + tid,       (v0 - mean) * inv * g[tid]       + bt[tid]);
  store_val(orow + tid + 256, (v1 - mean) * inv * g[tid + 256] + bt[tid + 256]);
  store_val(orow + tid + 512, (v2 - mean) * inv * g[tid + 512] + bt[tid + 512]);
}

// ---------------- MFMA flash attention ----------------
constexpr int SP2 = 224;
constexpr int VTS = 232;
__global__ __launch_bounds__(256) void attn_mfma_kernel(
    const __hip_bfloat16* __restrict__ qkv, __hip_bfloat16* __restrict__ ctx)
{
  const int b = blockIdx.x / NHn, h = blockIdx.x % NHn;
  const int tid = threadIdx.x;
  const int w = tid >> 6, lane = tid & 63;
  const int kg = lane >> 4, fr = lane & 15;

  __shared__ short Kl[SP2 * 64];       // 28672 B
  __shared__ short Vt[64 * VTS];       // 29696 B
  __shared__ short Pl[4 * 2048];       // 16384 B, per-wave [64][32]

  const size_t rstr = 3 * (size_t)Dn;  // 2304
  const __hip_bfloat16* base = qkv + (size_t)b * Sn * rstr;

  #pragma unroll
  for (int it = 0; it < 7; ++it) {
    const int i = it * 256 + tid;
    const int r = i >> 3, s = i & 7;
    const int rr = r < Sn ? r : Sn - 1;
    gload_lds16(base + (size_t)rr * rstr + Dn + h * HDn + ((s ^ (r & 7)) << 3),
                (char*)Kl + it * 4096 + w * 1024);
  }
  #pragma unroll
  for (int it = 0; it < 7; ++it) {
    const int i = it * 256 + tid;
    const int key = i >> 3, d0 = (i & 7) * 8;
    const int rr = key < Sn ? key : Sn - 1;
    bf16x8 v = *(const bf16x8*)(base + (size_t)rr * rstr + 2 * Dn + h * HDn + d0);
    #pragma unroll
    for (int e = 0; e < 8; ++e) Vt[(d0 + e) * VTS + key] = v[e];
  }
  const int qw = w * 64;
  bf16x8 qf[4][2];
  #pragma unroll
  for (int qt = 0; qt < 4; ++qt)
    #pragma unroll
    for (int kk = 0; kk < 2; ++kk) {
      int q = qw + qt * 16 + fr; if (q >= Sn) q = Sn - 1;
      qf[qt][kk] = *(const bf16x8*)(base + (size_t)q * rstr + h * HDn + kk * 32 + kg * 8);
    }
  __syncthreads();

  float mold[4][4], lsum[4][4];
  f32x4 cacc[4][4];
  #pragma unroll
  for (int qt = 0; qt < 4; ++qt)
    #pragma unroll
    for (int j = 0; j < 4; ++j) {
      mold[qt][j] = -1e30f; lsum[qt][j] = 0.f;
      cacc[qt][j] = (f32x4)(0.f);
    }
  const float scale = 0.125f;

  for (int kc = 0; kc < SP2; kc += 32) {
    f32x4 sacc[4][2];
    #pragma unroll
    for (int qt = 0; qt < 4; ++qt) { sacc[qt][0] = (f32x4)(0.f); sacc[qt][1] = (f32x4)(0.f); }
    #pragma unroll
    for (int nt = 0; nt < 2; ++nt) {
      const int key = kc + nt * 16 + fr;
      const bf16x8 kf0 = *(const bf16x8*)((const char*)Kl + key * 128 + ((kg ^ (key & 7)) << 4));
      const bf16x8 kf1 = *(const bf16x8*)((const char*)Kl + key * 128 + (((4 + kg) ^ (key & 7)) << 4));
      #pragma unroll
      for (int qt = 0; qt < 4; ++qt) {
        sacc[qt][nt] = __builtin_amdgcn_mfma_f32_16x16x32_bf16(qf[qt][0], kf0, sacc[qt][nt], 0, 0, 0);
        sacc[qt][nt] = __builtin_amdgcn_mfma_f32_16x16x32_bf16(qf[qt][1], kf1, sacc[qt][nt], 0, 0, 0);
      }
    }
    const float madd0 = (kc + fr < Sn) ? 0.f : -3e38f;
    const float madd1 = (kc + 16 + fr < Sn) ? 0.f : -3e38f;
    #pragma unroll
    for (int qt = 0; qt < 4; ++qt) {
      sacc[qt][0] = sacc[qt][0] * scale + (f32x4)(madd0);
      sacc[qt][1] = sacc[qt][1] * scale + (f32x4)(madd1);
    }
    #pragma unroll
    for (int qt = 0; qt < 4; ++qt) {
      #pragma unroll
      for (int j = 0; j < 4; ++j) {
        float t = fmaxf(sacc[qt][0][j], sacc[qt][1][j]);
        t = fmaxf(t, __shfl_xor(t, 1));
        t = fmaxf(t, __shfl_xor(t, 2));
        t = fmaxf(t, __shfl_xor(t, 4));
        t = fmaxf(t, __shfl_xor(t, 8));
        const float mn = fmaxf(mold[qt][j], t);
        const float corr = __expf(mold[qt][j] - mn);
        mold[qt][j] = mn;
        const float p0 = __expf(sacc[qt][0][j] - mn);
        const float p1 = __expf(sacc[qt][1][j] - mn);
        sacc[qt][0][j] = p0; sacc[qt][1][j] = p1;
        float ps = p0 + p1;
        ps += __shfl_xor(ps, 1); ps += __shfl_xor(ps, 2);
        ps += __shfl_xor(ps, 4); ps += __shfl_xor(ps, 8);
        lsum[qt][j] = lsum[qt][j] * corr + ps;
        #pragma unroll
        for (int ht = 0; ht < 4; ++ht) cacc[qt][ht][j] *= corr;
      }
      #pragma unroll
      for (int nt = 0; nt < 2; ++nt) {
        const int c = nt * 16 + fr;
        #pragma unroll
        for (int j = 0; j < 4; ++j) {
          const int r = qt * 16 + kg * 4 + j;
          Pl[w * 2048 + r * 32 + (((c >> 3) ^ (r & 3)) << 3) + (c & 7)] = f2bs(sacc[qt][nt][j]);
        }
      }
    }
    bf16x8 vf[4];
    #pragma unroll
    for (int ht = 0; ht < 4; ++ht)
      vf[ht] = *(const bf16x8*)(Vt + (ht * 16 + fr) * VTS + kc + kg * 8);
    #pragma unroll
    for (int qt = 0; qt < 4; ++qt) {
      const int r = qt * 16 + fr;
      const bf16x8 pf = *(const bf16x8*)(Pl + w * 2048 + r * 32 + ((kg ^ (r & 3)) << 3));
      #pragma unroll
      for (int ht = 0; ht < 4; ++ht)
        cacc[qt][ht] = __builtin_amdgcn_mfma_f32_16x16x32_bf16(pf, vf[ht], cacc[qt][ht], 0, 0, 0);
    }
  }
  __hip_bfloat16* cb = ctx + (size_t)b * Sn * Dn + h * HDn;
  #pragma unroll
  for (int qt = 0; qt < 4; ++qt)
    #pragma unroll
    for (int j = 0; j < 4; ++j) {
      const int q = qw + qt * 16 + kg * 4 + j;
      if (q < Sn) {
        const float inv = 1.f / lsum[qt][j];
        #pragma unroll
        for (int ht = 0; ht < 4; ++ht)
          cb[(size_t)q * Dn + ht * 16 + fr] = __float2bfloat16(cacc[qt][ht][j] * inv);
      }
    }
}

// ---------------- host side ----------------
using bf16 = __hip_bfloat16;

static inline void run_convT(const float* W, bf16* Wt, int K, int N, int L, hipStream_t st) {
  convT_kernel<<<dim3((N + 31) / 32, K / 32, L), 256, 0, st>>>(W, Wt, K, N);
}

extern "C" void kernel_launch(void* const* d_in, const int* in_sizes, int n_in,
                              void* d_out, int out_size, void* d_ws, size_t ws_size,
                              hipStream_t stream)
{
  const float* x      = (const float*)d_in[0];
  const float* emb_w  = (const float*)d_in[1];
  const float* emb_b  = (const float*)d_in[2];
  const float* cls    = (const float*)d_in[3];
  const float* pos    = (const float*)d_in[4];
  const float* pre_g  = (const float*)d_in[5];
  const float* pre_b  = (const float*)d_in[6];
  const float* ln1_g  = (const float*)d_in[7];
  const float* ln1_b  = (const float*)d_in[8];
  const float* qkv_w  = (const float*)d_in[9];
  const float* qkv_b  = (const float*)d_in[10];
  const float* proj_w = (const float*)d_in[11];
  const float* proj_b = (const float*)d_in[12];
  const float* ln2_g  = (const float*)d_in[13];
  const float* ln2_b  = (const float*)d_in[14];
  const float* fc1_w  = (const float*)d_in[15];
  const float* fc1_b  = (const float*)d_in[16];
  const float* fc2_w  = (const float*)d_in[17];
  const float* fc2_b  = (const float*)d_in[18];
  const float* post_g = (const float*)d_in[19];
  const float* post_b = (const float*)d_in[20];
  const float* h1_w   = (const float*)d_in[21];
  const float* h1_b   = (const float*)d_in[22];
  const float* h2_w   = (const float*)d_in[23];
  const float* h2_b   = (const float*)d_in[24];
  float* out = (float*)d_out;

  // workspace layout
  const size_t HN = (size_t)Mrows * Dn;
  float* hbuf = (float*)d_ws;                         // fp32 residual [M,768]
  bf16*  qkvb = (bf16*)(hbuf + HN);                   // bf16 [M,2304]; also fp32 [M,768] staging
  bf16*  abf1 = qkvb + (size_t)Mrows * 3 * Dn;        // bf16 [M,768]
  bf16*  abf2 = abf1 + HN;                            // bf16 [M,3072]; also fp32 staging
  bf16*  wtb  = abf2 + (size_t)Mrows * DFFn;          // bf16 scratch Wt (max 2304x768)

  // optional pre-converted all-layer weights (bf16, transposed)
  bf16* bigq = wtb + (size_t)2304 * 768;
  bf16* bigp = bigq + (size_t)Ln * 3 * Dn * Dn;
  bf16* big1 = bigp + (size_t)Ln * Dn * Dn;
  bf16* big2 = big1 + (size_t)Ln * Dn * DFFn;
  const size_t need_big = (size_t)((char*)(big2 + (size_t)Ln * DFFn * Dn) - (char*)d_ws);
  const bool useBig = ws_size >= need_big;

  const int gM = (Mrows + 127) / 128;                 // 50

  if (useBig) {
    run_convT(qkv_w,  bigq, Dn, 3 * Dn, Ln, stream);
    run_convT(proj_w, bigp, Dn, Dn,     Ln, stream);
    run_convT(fc1_w,  big1, Dn, DFFn,   Ln, stream);
    run_convT(fc2_w,  big2, DFFn, Dn,   Ln, stream);
  }

  // 1) patchify -> abf1 (bf16)
  patchify_kernel<<<(Bn * NPATCH * Dn) / 256, 256, 0, stream>>>(x, abf1);
  // 2) patch embed GEMM -> (float*)abf2
  run_convT(emb_w, wtb, Dn, Dn, 1, stream);
  bgemm_kernel<0, false, float><<<dim3(Dn / 128, NPATCH * Bn / 128), 256, 0, stream>>>(
      abf1, wtb, emb_b, nullptr, (float*)abf2, Bn * NPATCH, Dn, Dn);
  // 3) assemble cls+pos -> (float*)qkvb; pre-LN -> hbuf
  assemble_kernel<<<(Bn * Sn * Dn) / 256, 256, 0, stream>>>((float*)abf2, cls, pos, (float*)qkvb);
  ln_kernel<float><<<Mrows, 256, 0, stream>>>((float*)qkvb, (size_t)Dn, pre_g, pre_b, hbuf);

  for (int l = 0; l < Ln; ++l) {
    const float* g1 = ln1_g + (size_t)l * Dn;
    const float* b1 = ln1_b + (size_t)l * Dn;
    const float* qw = qkv_w + (size_t)l * Dn * 3 * Dn;
    const float* qb = qkv_b + (size_t)l * 3 * Dn;
    const float* pw = proj_w + (size_t)l * Dn * Dn;
    const float* pb = proj_b + (size_t)l * Dn;
    const float* g2 = ln2_g + (size_t)l * Dn;
    const float* b2 = ln2_b + (size_t)l * Dn;
    const float* f1w = fc1_w + (size_t)l * Dn * DFFn;
    const float* f1b = fc1_b + (size_t)l * DFFn;
    const float* f2w = fc2_w + (size_t)l * DFFn * Dn;
    const float* f2b = fc2_b + (size_t)l * Dn;

    const bf16* wq_t = useBig ? bigq + (size_t)l * 3 * Dn * Dn : wtb;
    const bf16* wp_t = useBig ? bigp + (size_t)l * Dn * Dn     : wtb;
    const bf16* w1_t = useBig ? big1 + (size_t)l * Dn * DFFn   : wtb;
    const bf16* w2_t = useBig ? big2 + (size_t)l * DFFn * Dn   : wtb;

    // LN1: h -> y (bf16)
    ln_kernel<bf16><<<Mrows, 256, 0, stream>>>(hbuf, (size_t)Dn, g1, b1, abf1);
    // QKV: y @ qw + qb -> qkvb (bf16 [M,3D])
    if (!useBig) run_convT(qw, wtb, Dn, 3 * Dn, 1, stream);
    bgemm_kernel<0, false, bf16><<<dim3(3 * Dn / 128, gM), 256, 0, stream>>>(
        abf1, wq_t, qb, nullptr, qkvb, Mrows, 3 * Dn, Dn);
    // attention -> abf1 (bf16 ctx)
    attn_mfma_kernel<<<Bn * NHn, 256, 0, stream>>>(qkvb, abf1);
    // proj + residual: h += ctx @ pw + pb
    if (!useBig) run_convT(pw, wtb, Dn, Dn, 1, stream);
    bgemm_kernel<0, true, float><<<dim3(Dn / 128, gM), 256, 0, stream>>>(
        abf1, wp_t, pb, hbuf, hbuf, Mrows, Dn, Dn);
    // LN2: h -> y (bf16)
    ln_kernel<bf16><<<Mrows, 256, 0, stream>>>(hbuf, (size_t)Dn, g2, b2, abf1);
    // fc1 + gelu -> abf2 (bf16 [M,DFF])
    if (!useBig) run_convT(f1w, wtb, Dn, DFFn, 1, stream);
    bgemm_kernel<1, false, bf16><<<dim3(DFFn / 128, gM), 256, 0, stream>>>(
        abf1, w1_t, f1b, nullptr, abf2, Mrows, DFFn, Dn);
    // fc2 + residual: h += m @ f2w + f2b
    if (!useBig) run_convT(f2w, wtb, DFFn, Dn, 1, stream);
    bgemm_kernel<0, true, float><<<dim3(Dn / 128, gM), 256, 0, stream>>>(
        abf2, w2_t, f2b, hbuf, hbuf, Mrows, Dn, DFFn);
  }

  // head: post-LN of h[:,0,:] -> t1; tanh GEMV -> t2; logits GEMV -> out
  float* t1 = (float*)abf2;
  float* t2 = t1 + Bn * Dn;
  ln_kernel<float><<<Bn, 256, 0, stream>>>(hbuf, (size_t)Sn * Dn, post_g, post_b, t1);
  run_convT(h1_w, wtb, Dn, Dn, 1, stream);
  hgemv_kernel<2><<<Bn * Dn / 4, 256, 0, stream>>>(t1, wtb, h1_b, t2, Dn, Dn);
  run_convT(h2_w, wtb, Dn, OUTn, 1, stream);
  hgemv_kernel<0><<<Bn * OUTn / 4, 256, 0, stream>>>(t2, wtb, h2_b, out, OUTn, Dn);
}

// Round 6
// 3713.500 us; speedup vs baseline: 6.4523x; 1.1402x over previous
//
#include <hip/hip_runtime.h>
#include <hip/hip_bf16.h>
#include <math.h>
#include <cstdint>

// ---------------- problem constants ----------------
constexpr int Bn   = 32;
constexpr int Dn   = 768;
constexpr int NHn  = 12;
constexpr int HDn  = 64;
constexpr int Ln   = 12;
constexpr int DFFn = 3072;
constexpr int OUTn = 1000;
constexpr int Sn   = 197;          // 14*14 + 1 tokens
constexpr int Mrows = Bn * Sn;     // 6304
constexpr int NPATCH = 196;

typedef __attribute__((ext_vector_type(8))) short bf16x8;
typedef __attribute__((ext_vector_type(4))) float f32x4;

__device__ inline void store_val(float* p, float v) { *p = v; }
__device__ inline void store_val(__hip_bfloat16* p, float v) { *p = __float2bfloat16(v); }
__device__ inline short f2bs(float f) {
  __hip_bfloat16 h = __float2bfloat16(f);
  return __builtin_bit_cast(short, h);
}

// async global->LDS, 16B per lane; LDS dest = wave-uniform base + lane*16
__device__ inline void gload_lds16(const void* g, void* l) {
  auto gp = (const __attribute__((address_space(1))) unsigned int*)(uintptr_t)g;
  auto lp = (__attribute__((address_space(3))) unsigned int*)(uintptr_t)l;
  __builtin_amdgcn_global_load_lds(gp, lp, 16, 0, 0);
}

// bijective XCD-chunk swizzle (m204): physical XCD gets a contiguous logical chunk
__device__ inline int xcd_swizzle(int orig, int nwg) {
  const int xcd = orig & 7, local = orig >> 3;
  const int q = nwg >> 3, r = nwg & 7;
  return (xcd < r) ? xcd * (q + 1) + local : r * (q + 1) + (xcd - r) * q + local;
}

// ---------------- bf16 MFMA GEMM (double-buffered, prefetch-before-compute) ----------------
// C[M,N] = act(A[M,K](bf16) @ Bt[N,K]^T(bf16) + bias) (+res fp32)
// 128x128 tile, BK=32, 4 waves. min-2-phase: stage(t+1) issued BEFORE compute(t);
// single __syncthreads (vmcnt(0)+lgkmcnt(0)+barrier) per K-iter.
template<int ACT, bool RES, typename OT>   // ACT: 0 none, 1 gelu(exact)
__global__ __launch_bounds__(256) void bgemm_kernel(
    const __hip_bfloat16* __restrict__ A,
    const __hip_bfloat16* __restrict__ Bt,
    const float* __restrict__ bias,
    const float* __restrict__ res,
    OT* __restrict__ out, int M, int N, int K)
{
  __shared__ __hip_bfloat16 As[2][128 * 32];   // 2 x 8 KB
  __shared__ __hip_bfloat16 Bs[2][128 * 32];
  const int tid  = threadIdx.x;
  const int w    = tid >> 6, lane = tid & 63;
  const int wm   = w >> 1,   wn   = w & 1;
  const int kg   = lane >> 4, fr = lane & 15;

  // XCD-aware block remap for L2 locality (A-panel neighbors adjacent in time)
  const int nwg = gridDim.x * gridDim.y;
  const int wg  = xcd_swizzle(blockIdx.y * gridDim.x + blockIdx.x, nwg);
  const int bm  = (wg / gridDim.x) * 128;
  const int bn  = (wg % gridDim.x) * 128;

  // per-lane staging geometry (constant across iters)
  const int obase0 = w * 2048;             // i=0 wave base
  const int obase1 = w * 2048 + 1024;      // i=1 wave base
  const int o0 = obase0 + lane * 16, o1 = obase1 + lane * 16;
  const int r0 = o0 >> 6,            r1 = o1 >> 6;
  const int ks0 = (((o0 >> 4) & 3) ^ (r0 & 3)) * 8;
  const int ks1 = (((o1 >> 4) & 3) ^ (r1 & 3)) * 8;
  const int ga0 = (bm + r0 >= M) ? M - 1 : bm + r0;
  const int ga1 = (bm + r1 >= M) ? M - 1 : bm + r1;
  const int gb0 = bn + r0, gb1 = bn + r1;

  f32x4 acc[4][4];
  #pragma unroll
  for (int i = 0; i < 4; ++i)
    #pragma unroll
    for (int j = 0; j < 4; ++j) acc[i][j] = (f32x4)(0.f);

  const int nt = K >> 5;

  // prologue: stage tile 0
  gload_lds16(A  + (size_t)ga0 * K + ks0, (char*)As[0] + obase0);
  gload_lds16(A  + (size_t)ga1 * K + ks1, (char*)As[0] + obase1);
  gload_lds16(Bt + (size_t)gb0 * K + ks0, (char*)Bs[0] + obase0);
  gload_lds16(Bt + (size_t)gb1 * K + ks1, (char*)Bs[0] + obase1);
  __syncthreads();

  int cur = 0;
  for (int t = 0; t < nt; ++t) {
    // issue next tile's loads (latency hidden under this tile's compute)
    if (t + 1 < nt) {
      const int k0 = (t + 1) << 5;
      gload_lds16(A  + (size_t)ga0 * K + k0 + ks0, (char*)As[cur ^ 1] + obase0);
      gload_lds16(A  + (size_t)ga1 * K + k0 + ks1, (char*)As[cur ^ 1] + obase1);
      gload_lds16(Bt + (size_t)gb0 * K + k0 + ks0, (char*)Bs[cur ^ 1] + obase0);
      gload_lds16(Bt + (size_t)gb1 * K + k0 + ks1, (char*)Bs[cur ^ 1] + obase1);
    }
    // compute current tile
    bf16x8 af[4], bfv[4];
    #pragma unroll
    for (int tt = 0; tt < 4; ++tt) {
      const int r = wm * 64 + tt * 16 + fr;
      af[tt]  = *(const bf16x8*)((const char*)As[cur] + r * 64 + ((kg ^ (r & 3)) << 4));
      const int c = wn * 64 + tt * 16 + fr;
      bfv[tt] = *(const bf16x8*)((const char*)Bs[cur] + c * 64 + ((kg ^ (c & 3)) << 4));
    }
    #pragma unroll
    for (int mt = 0; mt < 4; ++mt)
      #pragma unroll
      for (int nt2 = 0; nt2 < 4; ++nt2)
        acc[mt][nt2] = __builtin_amdgcn_mfma_f32_16x16x32_bf16(af[mt], bfv[nt2], acc[mt][nt2], 0, 0, 0);
    __syncthreads();   // vmcnt(0): prefetch landed; lgkm: reads done; all waves synced
    cur ^= 1;
  }

  // ---- epilogue: C/D col = lane&15, row = (lane>>4)*4 + j ----
  #pragma unroll
  for (int nt2 = 0; nt2 < 4; ++nt2) {
    const int cb = bn + wn * 64 + nt2 * 16 + fr;
    const float bs = bias[cb];
    #pragma unroll
    for (int mt = 0; mt < 4; ++mt) {
      #pragma unroll
      for (int j = 0; j < 4; ++j) {
        const int rb = bm + wm * 64 + mt * 16 + kg * 4 + j;
        if (rb >= M) continue;
        float v = acc[mt][nt2][j] + bs;
        if (ACT == 1) v = 0.5f * v * (1.f + erff(v * 0.70710678118654752f));
        if (RES) v += res[(size_t)rb * N + cb];
        store_val(out + (size_t)rb * N + cb, v);
      }
    }
  }
}

// ---------------- transpose-convert: W[z][K,N] fp32 -> Wt[z][N,K] bf16 (guarded) ----------------
__global__ __launch_bounds__(256) void convT_kernel(const float* __restrict__ W,
                                                    __hip_bfloat16* __restrict__ Wt,
                                                    int K, int N)
{
  const size_t lw = (size_t)K * N;
  const float* Wb = W + blockIdx.z * lw;
  __hip_bfloat16* Wo = Wt + blockIdx.z * lw;
  __shared__ float t[32][33];
  const int k0 = blockIdx.y * 32, n0 = blockIdx.x * 32;
  const int r  = threadIdx.x >> 3, c4 = (threadIdx.x & 7) * 4;
  const float* wp = Wb + (size_t)(k0 + r) * N + n0 + c4;
  float4 v = make_float4(0.f, 0.f, 0.f, 0.f);
  if (n0 + c4 + 3 < N) v = *(const float4*)wp;
  else {
    if (n0 + c4 + 0 < N) v.x = wp[0];
    if (n0 + c4 + 1 < N) v.y = wp[1];
    if (n0 + c4 + 2 < N) v.z = wp[2];
  }
  t[r][c4 + 0] = v.x; t[r][c4 + 1] = v.y; t[r][c4 + 2] = v.z; t[r][c4 + 3] = v.w;
  __syncthreads();
  const int n = n0 + r;
  if (n < N) {
    __hip_bfloat16* o = Wo + (size_t)n * K + k0 + c4;
    o[0] = __float2bfloat16(t[c4 + 0][r]);
    o[1] = __float2bfloat16(t[c4 + 1][r]);
    o[2] = __float2bfloat16(t[c4 + 2][r]);
    o[3] = __float2bfloat16(t[c4 + 3][r]);
  }
}

// ---------------- head GEMV: out[32,N] = act(A[32,K] @ Wt[N,K]^T + bias) ----------------
template<int ACT>   // 0 none, 2 tanh
__global__ __launch_bounds__(256) void hgemv_kernel(
    const float* __restrict__ A, const __hip_bfloat16* __restrict__ Wt,
    const float* __restrict__ bias, float* __restrict__ out, int N, int K)
{
  const int w = threadIdx.x >> 6, lane = threadIdx.x & 63;
  const int e = blockIdx.x * 4 + w;
  const int m = e & 31, n = e >> 5;
  if (n >= N) return;
  const float* a = A + (size_t)m * K;
  const __hip_bfloat16* wr = Wt + (size_t)n * K;
  float s = 0.f;
  for (int k = lane; k < K; k += 64)
    s = fmaf(a[k], __bfloat162float(wr[k]), s);
  #pragma unroll
  for (int o = 32; o > 0; o >>= 1) s += __shfl_xor(s, o);
  if (lane == 0) {
    float v = s + bias[n];
    if (ACT == 2) v = tanhf(v);
    out[(size_t)m * N + n] = v;
  }
}

// ---------------- patchify: x[B,C,224,224] -> patches[B*196, 768] bf16 ----------------
__global__ __launch_bounds__(256) void patchify_kernel(const float* __restrict__ x,
                                                       __hip_bfloat16* __restrict__ p)
{
  size_t i = (size_t)blockIdx.x * 256 + threadIdx.x;
  constexpr size_t total = (size_t)Bn * NPATCH * 768;
  if (i >= total) return;
  int k = (int)(i % 768);
  size_t m = i / 768;
  int b = (int)(m / NPATCH), pp = (int)(m % NPATCH);
  int py = pp / 14, px = pp % 14;
  int c = k >> 8, ph = (k >> 4) & 15, pw = k & 15;
  p[i] = __float2bfloat16(x[(((size_t)(b * 3 + c)) * 224 + py * 16 + ph) * 224 + px * 16 + pw]);
}

// ---------------- assemble: tokens+cls+pos -> [B,S,D] fp32 ----------------
__global__ __launch_bounds__(256) void assemble_kernel(const float* __restrict__ tok,
                                                       const float* __restrict__ cls,
                                                       const float* __restrict__ pos,
                                                       float* __restrict__ outp)
{
  size_t i = (size_t)blockIdx.x * 256 + threadIdx.x;
  constexpr size_t total = (size_t)Bn * Sn * Dn;
  if (i >= total) return;
  int d = (int)(i % Dn);
  size_t m = i / Dn;
  int s = (int)(m % Sn);
  size_t b = m / Sn;
  float v = (s == 0) ? cls[d] : tok[(b * NPATCH + (s - 1)) * Dn + d];
  outp[i] = v + pos[s * Dn + d];
}

// ---------------- LayerNorm over D=768, one block per row ----------------
template<typename OT>
__global__ __launch_bounds__(256) void ln_kernel(const float* __restrict__ x, size_t xstride,
                                                 const float* __restrict__ g,
                                                 const float* __restrict__ bt,
                                                 OT* __restrict__ out)
{
  const int row = blockIdx.x;
  const int tid = threadIdx.x;
  const float* xr = x + (size_t)row * xstride;
  float v0 = xr[tid], v1 = xr[tid + 256], v2 = xr[tid + 512];
  float s = v0 + v1 + v2;
  float q = v0 * v0 + v1 * v1 + v2 * v2;
  #pragma unroll
  for (int o = 32; o > 0; o >>= 1) { s += __shfl_down(s, o); q += __shfl_down(q, o); }
  __shared__ float sa[4], sb[4];
  int w = tid >> 6, lane = tid & 63;
  if (lane == 0) { sa[w] = s; sb[w] = q; }
  __syncthreads();
  if (tid == 0) {
    float ts = sa[0] + sa[1] + sa[2] + sa[3];
    float tq = sb[0] + sb[1] + sb[2] + sb[3];
    sa[0] = ts; sb[0] = tq;
  }
  __syncthreads();
  s = sa[0]; q = sb[0];
  const float mean = s * (1.f / 768.f);
  const float var  = q * (1.f / 768.f) - mean * mean;
  const float inv  = rsqrtf(var + 1e-5f);
  OT* orow = out + (size_t)row * Dn;
  store_val(orow + tid,       (v0 - mean) * inv * g[tid]       + bt[tid]);
  store_val(orow + tid + 256, (v1 - mean) * inv * g[tid + 256] + bt[tid + 256]);
  store_val(orow + tid + 512, (v2 - mean) * inv * g[tid + 512] + bt[tid + 512]);
}

// ---------------- MFMA flash attention ----------------
constexpr int SP2 = 224;
constexpr int VTS = 232;
__global__ __launch_bounds__(256) void attn_mfma_kernel(
    const __hip_bfloat16* __restrict__ qkv, __hip_bfloat16* __restrict__ ctx)
{
  const int b = blockIdx.x / NHn, h = blockIdx.x % NHn;
  const int tid = threadIdx.x;
  const int w = tid >> 6, lane = tid & 63;
  const int kg = lane >> 4, fr = lane & 15;

  __shared__ short Kl[SP2 * 64];       // 28672 B
  __shared__ short Vt[64 * VTS];       // 29696 B
  __shared__ short Pl[4 * 2048];       // 16384 B, per-wave [64][32]

  const size_t rstr = 3 * (size_t)Dn;  // 2304
  const __hip_bfloat16* base = qkv + (size_t)b * Sn * rstr;

  #pragma unroll
  for (int it = 0; it < 7; ++it) {
    const int i = it * 256 + tid;
    const int r = i >> 3, s = i & 7;
    const int rr = r < Sn ? r : Sn - 1;
    gload_lds16(base + (size_t)rr * rstr + Dn + h * HDn + ((s ^ (r & 7)) << 3),
                (char*)Kl + it * 4096 + w * 1024);
  }
  #pragma unroll
  for (int it = 0; it < 7; ++it) {
    const int i = it * 256 + tid;
    const int key = i >> 3, d0 = (i & 7) * 8;
    const int rr = key < Sn ? key : Sn - 1;
    bf16x8 v = *(const bf16x8*)(base + (size_t)rr * rstr + 2 * Dn + h * HDn + d0);
    #pragma unroll
    for (int e = 0; e < 8; ++e) Vt[(d0 + e) * VTS + key] = v[e];
  }
  const int qw = w * 64;
  bf16x8 qf[4][2];
  #pragma unroll
  for (int qt = 0; qt < 4; ++qt)
    #pragma unroll
    for (int kk = 0; kk < 2; ++kk) {
      int q = qw + qt * 16 + fr; if (q >= Sn) q = Sn - 1;
      qf[qt][kk] = *(const bf16x8*)(base + (size_t)q * rstr + h * HDn + kk * 32 + kg * 8);
    }
  __syncthreads();

  float mold[4][4], lsum[4][4];
  f32x4 cacc[4][4];
  #pragma unroll
  for (int qt = 0; qt < 4; ++qt)
    #pragma unroll
    for (int j = 0; j < 4; ++j) {
      mold[qt][j] = -1e30f; lsum[qt][j] = 0.f;
      cacc[qt][j] = (f32x4)(0.f);
    }
  const float scale = 0.125f;

  for (int kc = 0; kc < SP2; kc += 32) {
    f32x4 sacc[4][2];
    #pragma unroll
    for (int qt = 0; qt < 4; ++qt) { sacc[qt][0] = (f32x4)(0.f); sacc[qt][1] = (f32x4)(0.f); }
    #pragma unroll
    for (int nt = 0; nt < 2; ++nt) {
      const int key = kc + nt * 16 + fr;
      const bf16x8 kf0 = *(const bf16x8*)((const char*)Kl + key * 128 + ((kg ^ (key & 7)) << 4));
      const bf16x8 kf1 = *(const bf16x8*)((const char*)Kl + key * 128 + (((4 + kg) ^ (key & 7)) << 4));
      #pragma unroll
      for (int qt = 0; qt < 4; ++qt) {
        sacc[qt][nt] = __builtin_amdgcn_mfma_f32_16x16x32_bf16(qf[qt][0], kf0, sacc[qt][nt], 0, 0, 0);
        sacc[qt][nt] = __builtin_amdgcn_mfma_f32_16x16x32_bf16(qf[qt][1], kf1, sacc[qt][nt], 0, 0, 0);
      }
    }
    const float madd0 = (kc + fr < Sn) ? 0.f : -3e38f;
    const float madd1 = (kc + 16 + fr < Sn) ? 0.f : -3e38f;
    #pragma unroll
    for (int qt = 0; qt < 4; ++qt) {
      sacc[qt][0] = sacc[qt][0] * scale + (f32x4)(madd0);
      sacc[qt][1] = sacc[qt][1] * scale + (f32x4)(madd1);
    }
    #pragma unroll
    for (int qt = 0; qt < 4; ++qt) {
      #pragma unroll
      for (int j = 0; j < 4; ++j) {
        float t = fmaxf(sacc[qt][0][j], sacc[qt][1][j]);
        t = fmaxf(t, __shfl_xor(t, 1));
        t = fmaxf(t, __shfl_xor(t, 2));
        t = fmaxf(t, __shfl_xor(t, 4));
        t = fmaxf(t, __shfl_xor(t, 8));
        const float mn = fmaxf(mold[qt][j], t);
        const float corr = __expf(mold[qt][j] - mn);
        mold[qt][j] = mn;
        const float p0 = __expf(sacc[qt][0][j] - mn);
        const float p1 = __expf(sacc[qt][1][j] - mn);
        sacc[qt][0][j] = p0; sacc[qt][1][j] = p1;
        float ps = p0 + p1;
        ps += __shfl_xor(ps, 1); ps += __shfl_xor(ps, 2);
        ps += __shfl_xor(ps, 4); ps += __shfl_xor(ps, 8);
        lsum[qt][j] = lsum[qt][j] * corr + ps;
        #pragma unroll
        for (int ht = 0; ht < 4; ++ht) cacc[qt][ht][j] *= corr;
      }
      #pragma unroll
      for (int nt = 0; nt < 2; ++nt) {
        const int c = nt * 16 + fr;
        #pragma unroll
        for (int j = 0; j < 4; ++j) {
          const int r = qt * 16 + kg * 4 + j;
          Pl[w * 2048 + r * 32 + (((c >> 3) ^ (r & 3)) << 3) + (c & 7)] = f2bs(sacc[qt][nt][j]);
        }
      }
    }
    bf16x8 vf[4];
    #pragma unroll
    for (int ht = 0; ht < 4; ++ht)
      vf[ht] = *(const bf16x8*)(Vt + (ht * 16 + fr) * VTS + kc + kg * 8);
    #pragma unroll
    for (int qt = 0; qt < 4; ++qt) {
      const int r = qt * 16 + fr;
      const bf16x8 pf = *(const bf16x8*)(Pl + w * 2048 + r * 32 + ((kg ^ (r & 3)) << 3));
      #pragma unroll
      for (int ht = 0; ht < 4; ++ht)
        cacc[qt][ht] = __builtin_amdgcn_mfma_f32_16x16x32_bf16(pf, vf[ht], cacc[qt][ht], 0, 0, 0);
    }
  }
  __hip_bfloat16* cb = ctx + (size_t)b * Sn * Dn + h * HDn;
  #pragma unroll
  for (int qt = 0; qt < 4; ++qt)
    #pragma unroll
    for (int j = 0; j < 4; ++j) {
      const int q = qw + qt * 16 + kg * 4 + j;
      if (q < Sn) {
        const float inv = 1.f / lsum[qt][j];
        #pragma unroll
        for (int ht = 0; ht < 4; ++ht)
          cb[(size_t)q * Dn + ht * 16 + fr] = __float2bfloat16(cacc[qt][ht][j] * inv);
      }
    }
}

// ---------------- host side ----------------
using bf16 = __hip_bfloat16;

static inline void run_convT(const float* W, bf16* Wt, int K, int N, int L, hipStream_t st) {
  convT_kernel<<<dim3((N + 31) / 32, K / 32, L), 256, 0, st>>>(W, Wt, K, N);
}

extern "C" void kernel_launch(void* const* d_in, const int* in_sizes, int n_in,
                              void* d_out, int out_size, void* d_ws, size_t ws_size,
                              hipStream_t stream)
{
  const float* x      = (const float*)d_in[0];
  const float* emb_w  = (const float*)d_in[1];
  const float* emb_b  = (const float*)d_in[2];
  const float* cls    = (const float*)d_in[3];
  const float* pos    = (const float*)d_in[4];
  const float* pre_g  = (const float*)d_in[5];
  const float* pre_b  = (const float*)d_in[6];
  const float* ln1_g  = (const float*)d_in[7];
  const float* ln1_b  = (const float*)d_in[8];
  const float* qkv_w  = (const float*)d_in[9];
  const float* qkv_b  = (const float*)d_in[10];
  const float* proj_w = (const float*)d_in[11];
  const float* proj_b = (const float*)d_in[12];
  const float* ln2_g  = (const float*)d_in[13];
  const float* ln2_b  = (const float*)d_in[14];
  const float* fc1_w  = (const float*)d_in[15];
  const float* fc1_b  = (const float*)d_in[16];
  const float* fc2_w  = (const float*)d_in[17];
  const float* fc2_b  = (const float*)d_in[18];
  const float* post_g = (const float*)d_in[19];
  const float* post_b = (const float*)d_in[20];
  const float* h1_w   = (const float*)d_in[21];
  const float* h1_b   = (const float*)d_in[22];
  const float* h2_w   = (const float*)d_in[23];
  const float* h2_b   = (const float*)d_in[24];
  float* out = (float*)d_out;

  // workspace layout
  const size_t HN = (size_t)Mrows * Dn;
  float* hbuf = (float*)d_ws;                         // fp32 residual [M,768]
  bf16*  qkvb = (bf16*)(hbuf + HN);                   // bf16 [M,2304]; also fp32 [M,768] staging
  bf16*  abf1 = qkvb + (size_t)Mrows * 3 * Dn;        // bf16 [M,768]
  bf16*  abf2 = abf1 + HN;                            // bf16 [M,3072]; also fp32 staging
  bf16*  wtb  = abf2 + (size_t)Mrows * DFFn;          // bf16 scratch Wt (max 2304x768)

  // optional pre-converted all-layer weights (bf16, transposed)
  bf16* bigq = wtb + (size_t)2304 * 768;
  bf16* bigp = bigq + (size_t)Ln * 3 * Dn * Dn;
  bf16* big1 = bigp + (size_t)Ln * Dn * Dn;
  bf16* big2 = big1 + (size_t)Ln * Dn * DFFn;
  const size_t need_big = (size_t)((char*)(big2 + (size_t)Ln * DFFn * Dn) - (char*)d_ws);
  const bool useBig = ws_size >= need_big;

  const int gM = (Mrows + 127) / 128;                 // 50

  if (useBig) {
    run_convT(qkv_w,  bigq, Dn, 3 * Dn, Ln, stream);
    run_convT(proj_w, bigp, Dn, Dn,     Ln, stream);
    run_convT(fc1_w,  big1, Dn, DFFn,   Ln, stream);
    run_convT(fc2_w,  big2, DFFn, Dn,   Ln, stream);
  }

  // 1) patchify -> abf1 (bf16)
  patchify_kernel<<<(Bn * NPATCH * Dn) / 256, 256, 0, stream>>>(x, abf1);
  // 2) patch embed GEMM -> (float*)abf2
  run_convT(emb_w, wtb, Dn, Dn, 1, stream);
  bgemm_kernel<0, false, float><<<dim3(Dn / 128, NPATCH * Bn / 128), 256, 0, stream>>>(
      abf1, wtb, emb_b, nullptr, (float*)abf2, Bn * NPATCH, Dn, Dn);
  // 3) assemble cls+pos -> (float*)qkvb; pre-LN -> hbuf
  assemble_kernel<<<(Bn * Sn * Dn) / 256, 256, 0, stream>>>((float*)abf2, cls, pos, (float*)qkvb);
  ln_kernel<float><<<Mrows, 256, 0, stream>>>((float*)qkvb, (size_t)Dn, pre_g, pre_b, hbuf);

  for (int l = 0; l < Ln; ++l) {
    const float* g1 = ln1_g + (size_t)l * Dn;
    const float* b1 = ln1_b + (size_t)l * Dn;
    const float* qw = qkv_w + (size_t)l * Dn * 3 * Dn;
    const float* qb = qkv_b + (size_t)l * 3 * Dn;
    const float* pw = proj_w + (size_t)l * Dn * Dn;
    const float* pb = proj_b + (size_t)l * Dn;
    const float* g2 = ln2_g + (size_t)l * Dn;
    const float* b2 = ln2_b + (size_t)l * Dn;
    const float* f1w = fc1_w + (size_t)l * Dn * DFFn;
    const float* f1b = fc1_b + (size_t)l * DFFn;
    const float* f2w = fc2_w + (size_t)l * DFFn * Dn;
    const float* f2b = fc2_b + (size_t)l * Dn;

    const bf16* wq_t = useBig ? bigq + (size_t)l * 3 * Dn * Dn : wtb;
    const bf16* wp_t = useBig ? bigp + (size_t)l * Dn * Dn     : wtb;
    const bf16* w1_t = useBig ? big1 + (size_t)l * Dn * DFFn   : wtb;
    const bf16* w2_t = useBig ? big2 + (size_t)l * DFFn * Dn   : wtb;

    // LN1: h -> y (bf16)
    ln_kernel<bf16><<<Mrows, 256, 0, stream>>>(hbuf, (size_t)Dn, g1, b1, abf1);
    // QKV: y @ qw + qb -> qkvb (bf16 [M,3D])
    if (!useBig) run_convT(qw, wtb, Dn, 3 * Dn, 1, stream);
    bgemm_kernel<0, false, bf16><<<dim3(3 * Dn / 128, gM), 256, 0, stream>>>(
        abf1, wq_t, qb, nullptr, qkvb, Mrows, 3 * Dn, Dn);
    // attention -> abf1 (bf16 ctx)
    attn_mfma_kernel<<<Bn * NHn, 256, 0, stream>>>(qkvb, abf1);
    // proj + residual: h += ctx @ pw + pb
    if (!useBig) run_convT(pw, wtb, Dn, Dn, 1, stream);
    bgemm_kernel<0, true, float><<<dim3(Dn / 128, gM), 256, 0, stream>>>(
        abf1, wp_t, pb, hbuf, hbuf, Mrows, Dn, Dn);
    // LN2: h -> y (bf16)
    ln_kernel<bf16><<<Mrows, 256, 0, stream>>>(hbuf, (size_t)Dn, g2, b2, abf1);
    // fc1 + gelu -> abf2 (bf16 [M,DFF])
    if (!useBig) run_convT(f1w, wtb, Dn, DFFn, 1, stream);
    bgemm_kernel<1, false, bf16><<<dim3(DFFn / 128, gM), 256, 0, stream>>>(
        abf1, w1_t, f1b, nullptr, abf2, Mrows, DFFn, Dn);
    // fc2 + residual: h += m @ f2w + f2b
    if (!useBig) run_convT(f2w, wtb, DFFn, Dn, 1, stream);
    bgemm_kernel<0, true, float><<<dim3(Dn / 128, gM), 256, 0, stream>>>(
        abf2, w2_t, f2b, hbuf, hbuf, Mrows, Dn, DFFn);
  }

  // head: post-LN of h[:,0,:] -> t1; tanh GEMV -> t2; logits GEMV -> out
  float* t1 = (float*)abf2;
  float* t2 = t1 + Bn * Dn;
  ln_kernel<float><<<Bn, 256, 0, stream>>>(hbuf, (size_t)Sn * Dn, post_g, post_b, t1);
  run_convT(h1_w, wtb, Dn, Dn, 1, stream);
  hgemv_kernel<2><<<Bn * Dn / 4, 256, 0, stream>>>(t1, wtb, h1_b, t2, Dn, Dn);
  run_convT(h2_w, wtb, Dn, OUTn, 1, stream);
  hgemv_kernel<0><<<Bn * OUTn / 4, 256, 0, stream>>>(t2, wtb, h2_b, out, OUTn, Dn);
}

// Round 7
// 3476.060 us; speedup vs baseline: 6.8930x; 1.0683x over previous
//
#include <hip/hip_runtime.h>
#include <hip/hip_bf16.h>
#include <math.h>
#include <cstdint>

// ---------------- problem constants ----------------
constexpr int Bn   = 32;
constexpr int Dn   = 768;
constexpr int NHn  = 12;
constexpr int HDn  = 64;
constexpr int Ln   = 12;
constexpr int DFFn = 3072;
constexpr int OUTn = 1000;
constexpr int Sn   = 197;          // 14*14 + 1 tokens
constexpr int Mrows = Bn * Sn;     // 6304
constexpr int NPATCH = 196;

typedef __attribute__((ext_vector_type(8))) short bf16x8;
typedef __attribute__((ext_vector_type(4))) float f32x4;

__device__ inline void store_val(float* p, float v) { *p = v; }
__device__ inline void store_val(__hip_bfloat16* p, float v) { *p = __float2bfloat16(v); }
__device__ inline short f2bs(float f) {
  __hip_bfloat16 h = __float2bfloat16(f);
  return __builtin_bit_cast(short, h);
}

// async global->LDS, 16B per lane; LDS dest = wave-uniform base + lane*16
__device__ inline void gload_lds16(const void* g, void* l) {
  auto gp = (const __attribute__((address_space(1))) unsigned int*)(uintptr_t)g;
  auto lp = (__attribute__((address_space(3))) unsigned int*)(uintptr_t)l;
  __builtin_amdgcn_global_load_lds(gp, lp, 16, 0, 0);
}

// bijective XCD-chunk swizzle (m204)
__device__ inline int xcd_swizzle(int orig, int nwg) {
  const int xcd = orig & 7, local = orig >> 3;
  const int q = nwg >> 3, r = nwg & 7;
  return (xcd < r) ? xcd * (q + 1) + local : r * (q + 1) + (xcd - r) * q + local;
}

// ---------------- bf16 MFMA GEMM: 3-buffer ring, counted vmcnt (T4) ----------------
// C[M,N] = act(A[M,K](bf16) @ Bt[N,K]^T(bf16) + bias) (+res fp32)
// 128x128 tile, BK=32, 4 waves. Loads for tile t+1/t+2 stay in flight across
// barriers; per-iter wait is vmcnt(4) (NOT 0), raw s_barrier (no auto-drain).
template<int ACT, bool RES, typename OT>   // ACT: 0 none, 1 gelu(exact)
__global__ __launch_bounds__(256) void bgemm_kernel(
    const __hip_bfloat16* __restrict__ A,
    const __hip_bfloat16* __restrict__ Bt,
    const float* __restrict__ bias,
    const float* __restrict__ res,
    OT* __restrict__ out, int M, int N, int K)
{
  __shared__ __hip_bfloat16 As[3][128 * 32];   // 3 x 8 KB
  __shared__ __hip_bfloat16 Bs[3][128 * 32];
  const int tid  = threadIdx.x;
  const int w    = tid >> 6, lane = tid & 63;
  const int wm   = w >> 1,   wn   = w & 1;
  const int kg   = lane >> 4, fr = lane & 15;

  // XCD-aware block remap for L2 locality
  const int nwg = gridDim.x * gridDim.y;
  const int wg  = xcd_swizzle(blockIdx.y * gridDim.x + blockIdx.x, nwg);
  const int bm  = (wg / gridDim.x) * 128;
  const int bn  = (wg % gridDim.x) * 128;

  // per-lane staging geometry (constant across iters)
  const int obase0 = w * 2048;
  const int obase1 = w * 2048 + 1024;
  const int o0 = obase0 + lane * 16, o1 = obase1 + lane * 16;
  const int r0 = o0 >> 6,            r1 = o1 >> 6;
  const int ks0 = (((o0 >> 4) & 3) ^ (r0 & 3)) * 8;
  const int ks1 = (((o1 >> 4) & 3) ^ (r1 & 3)) * 8;
  const int ga0 = (bm + r0 >= M) ? M - 1 : bm + r0;
  const int ga1 = (bm + r1 >= M) ? M - 1 : bm + r1;
  const int gb0 = bn + r0, gb1 = bn + r1;

  f32x4 acc[4][4];
  #pragma unroll
  for (int i = 0; i < 4; ++i)
    #pragma unroll
    for (int j = 0; j < 4; ++j) acc[i][j] = (f32x4)(0.f);

  const int nt = K >> 5;   // >= 2 for all call sites (K = 768 or 3072)

  auto STAGE = [&](int t, int bi) {
    const int k0 = t << 5;
    gload_lds16(A  + (size_t)ga0 * K + k0 + ks0, (char*)As[bi] + obase0);
    gload_lds16(A  + (size_t)ga1 * K + k0 + ks1, (char*)As[bi] + obase1);
    gload_lds16(Bt + (size_t)gb0 * K + k0 + ks0, (char*)Bs[bi] + obase0);
    gload_lds16(Bt + (size_t)gb1 * K + k0 + ks1, (char*)Bs[bi] + obase1);
  };
  auto COMPUTE = [&](int bi) {
    bf16x8 af[4], bfv[4];
    #pragma unroll
    for (int tt = 0; tt < 4; ++tt) {
      const int r = wm * 64 + tt * 16 + fr;
      af[tt]  = *(const bf16x8*)((const char*)As[bi] + r * 64 + ((kg ^ (r & 3)) << 4));
      const int c = wn * 64 + tt * 16 + fr;
      bfv[tt] = *(const bf16x8*)((const char*)Bs[bi] + c * 64 + ((kg ^ (c & 3)) << 4));
    }
    #pragma unroll
    for (int mt = 0; mt < 4; ++mt)
      #pragma unroll
      for (int nt2 = 0; nt2 < 4; ++nt2)
        acc[mt][nt2] = __builtin_amdgcn_mfma_f32_16x16x32_bf16(af[mt], bfv[nt2], acc[mt][nt2], 0, 0, 0);
  };

  // prologue: tiles 0,1 in flight (8 loads/wave)
  STAGE(0, 0);
  STAGE(1, 1);

  int cur = 0;
  for (int t = 0; t < nt - 1; ++t) {
    // tile t landed when <=4 loads (tile t+1's) remain outstanding
    asm volatile("s_waitcnt vmcnt(4)" ::: "memory");
    __builtin_amdgcn_s_barrier();            // raw: in-flight loads NOT drained
    __builtin_amdgcn_sched_barrier(0);
    if (t + 2 < nt) {
      // overwrites buffer read at t-1: every wave past the barrier has executed
      // its t-1 MFMAs => its ds_reads of that buffer completed. Safe.
      int nb = cur + 2; if (nb >= 3) nb -= 3;
      STAGE(t + 2, nb);
    }
    COMPUTE(cur);
    ++cur; if (cur == 3) cur = 0;
  }
  // peeled last iteration: nothing left in flight to spare
  asm volatile("s_waitcnt vmcnt(0)" ::: "memory");
  __builtin_amdgcn_s_barrier();
  __builtin_amdgcn_sched_barrier(0);
  COMPUTE(cur);

  // ---- epilogue: C/D col = lane&15, row = (lane>>4)*4 + j ----
  #pragma unroll
  for (int nt2 = 0; nt2 < 4; ++nt2) {
    const int cb = bn + wn * 64 + nt2 * 16 + fr;
    const float bs = bias[cb];
    #pragma unroll
    for (int mt = 0; mt < 4; ++mt) {
      #pragma unroll
      for (int j = 0; j < 4; ++j) {
        const int rb = bm + wm * 64 + mt * 16 + kg * 4 + j;
        if (rb >= M) continue;
        float v = acc[mt][nt2][j] + bs;
        if (ACT == 1) v = 0.5f * v * (1.f + erff(v * 0.70710678118654752f));
        if (RES) v += res[(size_t)rb * N + cb];
        store_val(out + (size_t)rb * N + cb, v);
      }
    }
  }
}

// ---------------- transpose-convert: W[z][K,N] fp32 -> Wt[z][N,K] bf16 (guarded) ----------------
__global__ __launch_bounds__(256) void convT_kernel(const float* __restrict__ W,
                                                    __hip_bfloat16* __restrict__ Wt,
                                                    int K, int N)
{
  const size_t lw = (size_t)K * N;
  const float* Wb = W + blockIdx.z * lw;
  __hip_bfloat16* Wo = Wt + blockIdx.z * lw;
  __shared__ float t[32][33];
  const int k0 = blockIdx.y * 32, n0 = blockIdx.x * 32;
  const int r  = threadIdx.x >> 3, c4 = (threadIdx.x & 7) * 4;
  const float* wp = Wb + (size_t)(k0 + r) * N + n0 + c4;
  float4 v = make_float4(0.f, 0.f, 0.f, 0.f);
  if (n0 + c4 + 3 < N) v = *(const float4*)wp;
  else {
    if (n0 + c4 + 0 < N) v.x = wp[0];
    if (n0 + c4 + 1 < N) v.y = wp[1];
    if (n0 + c4 + 2 < N) v.z = wp[2];
  }
  t[r][c4 + 0] = v.x; t[r][c4 + 1] = v.y; t[r][c4 + 2] = v.z; t[r][c4 + 3] = v.w;
  __syncthreads();
  const int n = n0 + r;
  if (n < N) {
    __hip_bfloat16* o = Wo + (size_t)n * K + k0 + c4;
    o[0] = __float2bfloat16(t[c4 + 0][r]);
    o[1] = __float2bfloat16(t[c4 + 1][r]);
    o[2] = __float2bfloat16(t[c4 + 2][r]);
    o[3] = __float2bfloat16(t[c4 + 3][r]);
  }
}

// ---------------- head GEMV: out[32,N] = act(A[32,K] @ Wt[N,K]^T + bias) ----------------
template<int ACT>   // 0 none, 2 tanh
__global__ __launch_bounds__(256) void hgemv_kernel(
    const float* __restrict__ A, const __hip_bfloat16* __restrict__ Wt,
    const float* __restrict__ bias, float* __restrict__ out, int N, int K)
{
  const int w = threadIdx.x >> 6, lane = threadIdx.x & 63;
  const int e = blockIdx.x * 4 + w;
  const int m = e & 31, n = e >> 5;
  if (n >= N) return;
  const float* a = A + (size_t)m * K;
  const __hip_bfloat16* wr = Wt + (size_t)n * K;
  float s = 0.f;
  for (int k = lane; k < K; k += 64)
    s = fmaf(a[k], __bfloat162float(wr[k]), s);
  #pragma unroll
  for (int o = 32; o > 0; o >>= 1) s += __shfl_xor(s, o);
  if (lane == 0) {
    float v = s + bias[n];
    if (ACT == 2) v = tanhf(v);
    out[(size_t)m * N + n] = v;
  }
}

// ---------------- patchify: x[B,C,224,224] -> patches[B*196, 768] bf16 ----------------
__global__ __launch_bounds__(256) void patchify_kernel(const float* __restrict__ x,
                                                       __hip_bfloat16* __restrict__ p)
{
  size_t i = (size_t)blockIdx.x * 256 + threadIdx.x;
  constexpr size_t total = (size_t)Bn * NPATCH * 768;
  if (i >= total) return;
  int k = (int)(i % 768);
  size_t m = i / 768;
  int b = (int)(m / NPATCH), pp = (int)(m % NPATCH);
  int py = pp / 14, px = pp % 14;
  int c = k >> 8, ph = (k >> 4) & 15, pw = k & 15;
  p[i] = __float2bfloat16(x[(((size_t)(b * 3 + c)) * 224 + py * 16 + ph) * 224 + px * 16 + pw]);
}

// ---------------- assemble: tokens+cls+pos -> [B,S,D] fp32 ----------------
__global__ __launch_bounds__(256) void assemble_kernel(const float* __restrict__ tok,
                                                       const float* __restrict__ cls,
                                                       const float* __restrict__ pos,
                                                       float* __restrict__ outp)
{
  size_t i = (size_t)blockIdx.x * 256 + threadIdx.x;
  constexpr size_t total = (size_t)Bn * Sn * Dn;
  if (i >= total) return;
  int d = (int)(i % Dn);
  size_t m = i / Dn;
  int s = (int)(m % Sn);
  size_t b = m / Sn;
  float v = (s == 0) ? cls[d] : tok[(b * NPATCH + (s - 1)) * Dn + d];
  outp[i] = v + pos[s * Dn + d];
}

// ---------------- LayerNorm over D=768, one block per row ----------------
template<typename OT>
__global__ __launch_bounds__(256) void ln_kernel(const float* __restrict__ x, size_t xstride,
                                                 const float* __restrict__ g,
                                                 const float* __restrict__ bt,
                                                 OT* __restrict__ out)
{
  const int row = blockIdx.x;
  const int tid = threadIdx.x;
  const float* xr = x + (size_t)row * xstride;
  float v0 = xr[tid], v1 = xr[tid + 256], v2 = xr[tid + 512];
  float s = v0 + v1 + v2;
  float q = v0 * v0 + v1 * v1 + v2 * v2;
  #pragma unroll
  for (int o = 32; o > 0; o >>= 1) { s += __shfl_down(s, o); q += __shfl_down(q, o); }
  __shared__ float sa[4], sb[4];
  int w = tid >> 6, lane = tid & 63;
  if (lane == 0) { sa[w] = s; sb[w] = q; }
  __syncthreads();
  if (tid == 0) {
    float ts = sa[0] + sa[1] + sa[2] + sa[3];
    float tq = sb[0] + sb[1] + sb[2] + sb[3];
    sa[0] = ts; sb[0] = tq;
  }
  __syncthreads();
  s = sa[0]; q = sb[0];
  const float mean = s * (1.f / 768.f);
  const float var  = q * (1.f / 768.f) - mean * mean;
  const float inv  = rsqrtf(var + 1e-5f);
  OT* orow = out + (size_t)row * Dn;
  store_val(orow + tid,       (v0 - mean) * inv * g[tid]       + bt[tid]);
  store_val(orow + tid + 256, (v1 - mean) * inv * g[tid + 256] + bt[tid + 256]);
  store_val(orow + tid + 512, (v2 - mean) * inv * g[tid + 512] + bt[tid + 512]);
}

// ---------------- MFMA flash attention ----------------
constexpr int SP2 = 224;
constexpr int VTS = 232;
__global__ __launch_bounds__(256) void attn_mfma_kernel(
    const __hip_bfloat16* __restrict__ qkv, __hip_bfloat16* __restrict__ ctx)
{
  const int b = blockIdx.x / NHn, h = blockIdx.x % NHn;
  const int tid = threadIdx.x;
  const int w = tid >> 6, lane = tid & 63;
  const int kg = lane >> 4, fr = lane & 15;

  __shared__ short Kl[SP2 * 64];       // 28672 B
  __shared__ short Vt[64 * VTS];       // 29696 B
  __shared__ short Pl[4 * 2048];       // 16384 B, per-wave [64][32]

  const size_t rstr = 3 * (size_t)Dn;  // 2304
  const __hip_bfloat16* base = qkv + (size_t)b * Sn * rstr;

  #pragma unroll
  for (int it = 0; it < 7; ++it) {
    const int i = it * 256 + tid;
    const int r = i >> 3, s = i & 7;
    const int rr = r < Sn ? r : Sn - 1;
    gload_lds16(base + (size_t)rr * rstr + Dn + h * HDn + ((s ^ (r & 7)) << 3),
                (char*)Kl + it * 4096 + w * 1024);
  }
  #pragma unroll
  for (int it = 0; it < 7; ++it) {
    const int i = it * 256 + tid;
    const int key = i >> 3, d0 = (i & 7) * 8;
    const int rr = key < Sn ? key : Sn - 1;
    bf16x8 v = *(const bf16x8*)(base + (size_t)rr * rstr + 2 * Dn + h * HDn + d0);
    #pragma unroll
    for (int e = 0; e < 8; ++e) Vt[(d0 + e) * VTS + key] = v[e];
  }
  const int qw = w * 64;
  bf16x8 qf[4][2];
  #pragma unroll
  for (int qt = 0; qt < 4; ++qt)
    #pragma unroll
    for (int kk = 0; kk < 2; ++kk) {
      int q = qw + qt * 16 + fr; if (q >= Sn) q = Sn - 1;
      qf[qt][kk] = *(const bf16x8*)(base + (size_t)q * rstr + h * HDn + kk * 32 + kg * 8);
    }
  __syncthreads();

  float mold[4][4], lsum[4][4];
  f32x4 cacc[4][4];
  #pragma unroll
  for (int qt = 0; qt < 4; ++qt)
    #pragma unroll
    for (int j = 0; j < 4; ++j) {
      mold[qt][j] = -1e30f; lsum[qt][j] = 0.f;
      cacc[qt][j] = (f32x4)(0.f);
    }
  const float scale = 0.125f;

  for (int kc = 0; kc < SP2; kc += 32) {
    f32x4 sacc[4][2];
    #pragma unroll
    for (int qt = 0; qt < 4; ++qt) { sacc[qt][0] = (f32x4)(0.f); sacc[qt][1] = (f32x4)(0.f); }
    #pragma unroll
    for (int nt = 0; nt < 2; ++nt) {
      const int key = kc + nt * 16 + fr;
      const bf16x8 kf0 = *(const bf16x8*)((const char*)Kl + key * 128 + ((kg ^ (key & 7)) << 4));
      const bf16x8 kf1 = *(const bf16x8*)((const char*)Kl + key * 128 + (((4 + kg) ^ (key & 7)) << 4));
      #pragma unroll
      for (int qt = 0; qt < 4; ++qt) {
        sacc[qt][nt] = __builtin_amdgcn_mfma_f32_16x16x32_bf16(qf[qt][0], kf0, sacc[qt][nt], 0, 0, 0);
        sacc[qt][nt] = __builtin_amdgcn_mfma_f32_16x16x32_bf16(qf[qt][1], kf1, sacc[qt][nt], 0, 0, 0);
      }
    }
    const float madd0 = (kc + fr < Sn) ? 0.f : -3e38f;
    const float madd1 = (kc + 16 + fr < Sn) ? 0.f : -3e38f;
    #pragma unroll
    for (int qt = 0; qt < 4; ++qt) {
      sacc[qt][0] = sacc[qt][0] * scale + (f32x4)(madd0);
      sacc[qt][1] = sacc[qt][1] * scale + (f32x4)(madd1);
    }
    #pragma unroll
    for (int qt = 0; qt < 4; ++qt) {
      #pragma unroll
      for (int j = 0; j < 4; ++j) {
        float t = fmaxf(sacc[qt][0][j], sacc[qt][1][j]);
        t = fmaxf(t, __shfl_xor(t, 1));
        t = fmaxf(t, __shfl_xor(t, 2));
        t = fmaxf(t, __shfl_xor(t, 4));
        t = fmaxf(t, __shfl_xor(t, 8));
        const float mn = fmaxf(mold[qt][j], t);
        const float corr = __expf(mold[qt][j] - mn);
        mold[qt][j] = mn;
        const float p0 = __expf(sacc[qt][0][j] - mn);
        const float p1 = __expf(sacc[qt][1][j] - mn);
        sacc[qt][0][j] = p0; sacc[qt][1][j] = p1;
        float ps = p0 + p1;
        ps += __shfl_xor(ps, 1); ps += __shfl_xor(ps, 2);
        ps += __shfl_xor(ps, 4); ps += __shfl_xor(ps, 8);
        lsum[qt][j] = lsum[qt][j] * corr + ps;
        #pragma unroll
        for (int ht = 0; ht < 4; ++ht) cacc[qt][ht][j] *= corr;
      }
      #pragma unroll
      for (int nt = 0; nt < 2; ++nt) {
        const int c = nt * 16 + fr;
        #pragma unroll
        for (int j = 0; j < 4; ++j) {
          const int r = qt * 16 + kg * 4 + j;
          Pl[w * 2048 + r * 32 + (((c >> 3) ^ (r & 3)) << 3) + (c & 7)] = f2bs(sacc[qt][nt][j]);
        }
      }
    }
    bf16x8 vf[4];
    #pragma unroll
    for (int ht = 0; ht < 4; ++ht)
      vf[ht] = *(const bf16x8*)(Vt + (ht * 16 + fr) * VTS + kc + kg * 8);
    #pragma unroll
    for (int qt = 0; qt < 4; ++qt) {
      const int r = qt * 16 + fr;
      const bf16x8 pf = *(const bf16x8*)(Pl + w * 2048 + r * 32 + ((kg ^ (r & 3)) << 3));
      #pragma unroll
      for (int ht = 0; ht < 4; ++ht)
        cacc[qt][ht] = __builtin_amdgcn_mfma_f32_16x16x32_bf16(pf, vf[ht], cacc[qt][ht], 0, 0, 0);
    }
  }
  __hip_bfloat16* cb = ctx + (size_t)b * Sn * Dn + h * HDn;
  #pragma unroll
  for (int qt = 0; qt < 4; ++qt)
    #pragma unroll
    for (int j = 0; j < 4; ++j) {
      const int q = qw + qt * 16 + kg * 4 + j;
      if (q < Sn) {
        const float inv = 1.f / lsum[qt][j];
        #pragma unroll
        for (int ht = 0; ht < 4; ++ht)
          cb[(size_t)q * Dn + ht * 16 + fr] = __float2bfloat16(cacc[qt][ht][j] * inv);
      }
    }
}

// ---------------- host side ----------------
using bf16 = __hip_bfloat16;

static inline void run_convT(const float* W, bf16* Wt, int K, int N, int L, hipStream_t st) {
  convT_kernel<<<dim3((N + 31) / 32, K / 32, L), 256, 0, st>>>(W, Wt, K, N);
}

extern "C" void kernel_launch(void* const* d_in, const int* in_sizes, int n_in,
                              void* d_out, int out_size, void* d_ws, size_t ws_size,
                              hipStream_t stream)
{
  const float* x      = (const float*)d_in[0];
  const float* emb_w  = (const float*)d_in[1];
  const float* emb_b  = (const float*)d_in[2];
  const float* cls    = (const float*)d_in[3];
  const float* pos    = (const float*)d_in[4];
  const float* pre_g  = (const float*)d_in[5];
  const float* pre_b  = (const float*)d_in[6];
  const float* ln1_g  = (const float*)d_in[7];
  const float* ln1_b  = (const float*)d_in[8];
  const float* qkv_w  = (const float*)d_in[9];
  const float* qkv_b  = (const float*)d_in[10];
  const float* proj_w = (const float*)d_in[11];
  const float* proj_b = (const float*)d_in[12];
  const float* ln2_g  = (const float*)d_in[13];
  const float* ln2_b  = (const float*)d_in[14];
  const float* fc1_w  = (const float*)d_in[15];
  const float* fc1_b  = (const float*)d_in[16];
  const float* fc2_w  = (const float*)d_in[17];
  const float* fc2_b  = (const float*)d_in[18];
  const float* post_g = (const float*)d_in[19];
  const float* post_b = (const float*)d_in[20];
  const float* h1_w   = (const float*)d_in[21];
  const float* h1_b   = (const float*)d_in[22];
  const float* h2_w   = (const float*)d_in[23];
  const float* h2_b   = (const float*)d_in[24];
  float* out = (float*)d_out;

  // workspace layout
  const size_t HN = (size_t)Mrows * Dn;
  float* hbuf = (float*)d_ws;                         // fp32 residual [M,768]
  bf16*  qkvb = (bf16*)(hbuf + HN);                   // bf16 [M,2304]; also fp32 [M,768] staging
  bf16*  abf1 = qkvb + (size_t)Mrows * 3 * Dn;        // bf16 [M,768]
  bf16*  abf2 = abf1 + HN;                            // bf16 [M,3072]; also fp32 staging
  bf16*  wtb  = abf2 + (size_t)Mrows * DFFn;          // bf16 scratch Wt (max 2304x768)

  // optional pre-converted all-layer weights (bf16, transposed)
  bf16* bigq = wtb + (size_t)2304 * 768;
  bf16* bigp = bigq + (size_t)Ln * 3 * Dn * Dn;
  bf16* big1 = bigp + (size_t)Ln * Dn * Dn;
  bf16* big2 = big1 + (size_t)Ln * Dn * DFFn;
  const size_t need_big = (size_t)((char*)(big2 + (size_t)Ln * DFFn * Dn) - (char*)d_ws);
  const bool useBig = ws_size >= need_big;

  const int gM = (Mrows + 127) / 128;                 // 50

  if (useBig) {
    run_convT(qkv_w,  bigq, Dn, 3 * Dn, Ln, stream);
    run_convT(proj_w, bigp, Dn, Dn,     Ln, stream);
    run_convT(fc1_w,  big1, Dn, DFFn,   Ln, stream);
    run_convT(fc2_w,  big2, DFFn, Dn,   Ln, stream);
  }

  // 1) patchify -> abf1 (bf16)
  patchify_kernel<<<(Bn * NPATCH * Dn) / 256, 256, 0, stream>>>(x, abf1);
  // 2) patch embed GEMM -> (float*)abf2
  run_convT(emb_w, wtb, Dn, Dn, 1, stream);
  bgemm_kernel<0, false, float><<<dim3(Dn / 128, NPATCH * Bn / 128), 256, 0, stream>>>(
      abf1, wtb, emb_b, nullptr, (float*)abf2, Bn * NPATCH, Dn, Dn);
  // 3) assemble cls+pos -> (float*)qkvb; pre-LN -> hbuf
  assemble_kernel<<<(Bn * Sn * Dn) / 256, 256, 0, stream>>>((float*)abf2, cls, pos, (float*)qkvb);
  ln_kernel<float><<<Mrows, 256, 0, stream>>>((float*)qkvb, (size_t)Dn, pre_g, pre_b, hbuf);

  for (int l = 0; l < Ln; ++l) {
    const float* g1 = ln1_g + (size_t)l * Dn;
    const float* b1 = ln1_b + (size_t)l * Dn;
    const float* qw = qkv_w + (size_t)l * Dn * 3 * Dn;
    const float* qb = qkv_b + (size_t)l * 3 * Dn;
    const float* pw = proj_w + (size_t)l * Dn * Dn;
    const float* pb = proj_b + (size_t)l * Dn;
    const float* g2 = ln2_g + (size_t)l * Dn;
    const float* b2 = ln2_b + (size_t)l * Dn;
    const float* f1w = fc1_w + (size_t)l * Dn * DFFn;
    const float* f1b = fc1_b + (size_t)l * DFFn;
    const float* f2w = fc2_w + (size_t)l * DFFn * Dn;
    const float* f2b = fc2_b + (size_t)l * Dn;

    const bf16* wq_t = useBig ? bigq + (size_t)l * 3 * Dn * Dn : wtb;
    const bf16* wp_t = useBig ? bigp + (size_t)l * Dn * Dn     : wtb;
    const bf16* w1_t = useBig ? big1 + (size_t)l * Dn * DFFn   : wtb;
    const bf16* w2_t = useBig ? big2 + (size_t)l * DFFn * Dn   : wtb;

    // LN1: h -> y (bf16)
    ln_kernel<bf16><<<Mrows, 256, 0, stream>>>(hbuf, (size_t)Dn, g1, b1, abf1);
    // QKV: y @ qw + qb -> qkvb (bf16 [M,3D])
    if (!useBig) run_convT(qw, wtb, Dn, 3 * Dn, 1, stream);
    bgemm_kernel<0, false, bf16><<<dim3(3 * Dn / 128, gM), 256, 0, stream>>>(
        abf1, wq_t, qb, nullptr, qkvb, Mrows, 3 * Dn, Dn);
    // attention -> abf1 (bf16 ctx)
    attn_mfma_kernel<<<Bn * NHn, 256, 0, stream>>>(qkvb, abf1);
    // proj + residual: h += ctx @ pw + pb
    if (!useBig) run_convT(pw, wtb, Dn, Dn, 1, stream);
    bgemm_kernel<0, true, float><<<dim3(Dn / 128, gM), 256, 0, stream>>>(
        abf1, wp_t, pb, hbuf, hbuf, Mrows, Dn, Dn);
    // LN2: h -> y (bf16)
    ln_kernel<bf16><<<Mrows, 256, 0, stream>>>(hbuf, (size_t)Dn, g2, b2, abf1);
    // fc1 + gelu -> abf2 (bf16 [M,DFF])
    if (!useBig) run_convT(f1w, wtb, Dn, DFFn, 1, stream);
    bgemm_kernel<1, false, bf16><<<dim3(DFFn / 128, gM), 256, 0, stream>>>(
        abf1, w1_t, f1b, nullptr, abf2, Mrows, DFFn, Dn);
    // fc2 + residual: h += m @ f2w + f2b
    if (!useBig) run_convT(f2w, wtb, DFFn, Dn, 1, stream);
    bgemm_kernel<0, true, float><<<dim3(Dn / 128, gM), 256, 0, stream>>>(
        abf2, w2_t, f2b, hbuf, hbuf, Mrows, Dn, DFFn);
  }

  // head: post-LN of h[:,0,:] -> t1; tanh GEMV -> t2; logits GEMV -> out
  float* t1 = (float*)abf2;
  float* t2 = t1 + Bn * Dn;
  ln_kernel<float><<<Bn, 256, 0, stream>>>(hbuf, (size_t)Sn * Dn, post_g, post_b, t1);
  run_convT(h1_w, wtb, Dn, Dn, 1, stream);
  hgemv_kernel<2><<<Bn * Dn / 4, 256, 0, stream>>>(t1, wtb, h1_b, t2, Dn, Dn);
  run_convT(h2_w, wtb, Dn, OUTn, 1, stream);
  hgemv_kernel<0><<<Bn * OUTn / 4, 256, 0, stream>>>(t2, wtb, h2_b, out, OUTn, Dn);
}